// Round 5
// baseline (1247.388 us; speedup 1.0000x reference)
//
#include <hip/hip_runtime.h>
#include <hip/hip_bf16.h>
#include <math.h>

#define E_EDGES 50000
#define NN 5000
#define WCH 6250          // edges per layer-1 w chunk (8 chunks)

typedef __hip_bfloat16 bf16;
typedef __attribute__((ext_vector_type(8))) short short8;
typedef __attribute__((ext_vector_type(4))) float f32x4;

__device__ __forceinline__ float b2f(bf16 v) { return __bfloat162float(v); }
__device__ __forceinline__ float siluf(float x) { return x / (1.0f + __expf(-x)); }

// ---------------- CG / path constant tables ----------------
__constant__ int   C112_I[11] = {0,2,0,1,1,2, 0,1,2, 0,2};
__constant__ int   C112_J[11] = {2,0,1,0,2,1, 0,1,2, 0,2};
__constant__ int   C112_K[11] = {0,0,1,1,3,3, 2,2,2, 4,4};
__constant__ float C112_V[11] = {
  0.3162277660168379f, 0.3162277660168379f, 0.3162277660168379f,
  0.3162277660168379f, 0.3162277660168379f, 0.3162277660168379f,
 -0.1825741858350554f, 0.3651483716701107f,-0.1825741858350554f,
 -0.3162277660168379f, 0.3162277660168379f};

__constant__ int   C222_I[25] = {0,0,2, 0,0,1,1,3,3, 1,1,2, 1,1,4, 2, 2,3,3, 2,4,4, 3,3,4};
__constant__ int   C222_J[25] = {0,2,0, 1,3,0,3,0,1, 1,2,1, 1,4,1, 2, 3,2,3, 4,2,4, 3,4,3};
__constant__ int   C222_K[25] = {2,0,0, 3,1,3,0,1,0, 2,1,1, 4,1,1, 2, 3,3,2, 4,4,2, 4,3,3};
__constant__ float C222_V[25] = {
  0.2390457218668787f, 0.2390457218668787f, 0.2390457218668787f,
 -0.2070196678027063f,-0.2070196678027063f,-0.2070196678027063f,
 -0.2070196678027063f,-0.2070196678027063f,-0.2070196678027063f,
 -0.1195228609334394f,-0.1195228609334394f,-0.1195228609334394f,
  0.2070196678027063f, 0.2070196678027063f, 0.2070196678027063f,
 -0.2390457218668787f,
 -0.1195228609334394f,-0.1195228609334394f,-0.1195228609334394f,
  0.2390457218668787f, 0.2390457218668787f, 0.2390457218668787f,
 -0.2070196678027063f,-0.2070196678027063f,-0.2070196678027063f};

// per-path scale (alpha, diag-CG folded)
__constant__ float P_SC_[11] = {
  0.1336306209562122f, 0.1178511301977579f, 0.125f, 0.1178511301977579f,
  0.0771516749810460f, 0.2795084971874737f, 0.2041241452319315f, 0.125f,
  0.2041241452319315f, 0.0597614304667197f, 0.2795084971874737f};

// ---------------- kernels ----------------

__global__ void k_prep(const float* __restrict__ evec, const float* __restrict__ elen,
                       float* __restrict__ shb, float* __restrict__ bc) {
  int e = blockIdx.x * 256 + threadIdx.x;
  if (e >= E_EDGES) return;
  float x = evec[3*e+0], y = evec[3*e+1], z = evec[3*e+2];
  float r = elen[e];
  float inv = 1.0f / (r + 1e-8f);
  float ux = x*inv, uy = y*inv, uz = z*inv;
  const float s3 = 1.7320508075688772f, s5 = 2.2360679774997896f, s15 = 3.8729833462074170f;
  float* sh = shb + (size_t)e*12;
  sh[0] = 1.0f;
  sh[1] = s3*uy; sh[2] = s3*uz; sh[3] = s3*ux;
  sh[4] = s15*ux*uy; sh[5] = s15*uy*uz; sh[6] = 0.5f*s5*(3.0f*uz*uz - 1.0f);
  sh[7] = s15*ux*uz; sh[8] = 0.5f*s15*(ux*ux - uy*uy);
  sh[9] = 0.f; sh[10] = 0.f; sh[11] = 0.f;
  float rr = fmaxf(r, 1e-8f);
  const float pi = 3.14159265358979f;
  float xr = r * 0.2f;
  float cut = (xr < 1.0f) ? 0.5f*(1.0f + cosf(pi*xr)) : 0.0f;
  float fb = pi * 0.2f;
  for (int k = 1; k <= 8; ++k)
    bc[(size_t)e*8 + (k-1)] = sinf(fb*(float)k*r)/rr * cut;
}

// fold rad_w2 into wnn*_w1:  M0t[c][k] = sum_m rad_w2[k][m] * wnn0_w1[m][c]
// bias0[c] = sum_m rad_b2[m] * wnn0_w1[m][c]   (same for M1t/bias1 with wnn1_w1)
__global__ void k_fuse(const float* __restrict__ w2, const float* __restrict__ b2,
                       const float* __restrict__ w01, const float* __restrict__ w11,
                       float* __restrict__ M0t, float* __restrict__ M1t,
                       float* __restrict__ bias0, float* __restrict__ bias1) {
  int i = blockIdx.x*256 + threadIdx.x;   // 4096
  int c = i >> 6, k = i & 63;
  float a0 = 0.f, a1 = 0.f;
  for (int m = 0; m < 64; ++m) {
    float wv = w2[k*64 + m];
    a0 += wv * w01[m*64 + c];
    a1 += wv * w11[m*64 + c];
  }
  M0t[c*64 + k] = a0;
  M1t[c*64 + k] = a1;
  if (k == 0) {
    float s0 = 0.f, s1 = 0.f;
    for (int m = 0; m < 64; ++m) {
      s0 += b2[m] * w01[m*64 + c];
      s1 += b2[m] * w11[m*64 + c];
    }
    bias0[c] = s0;
    bias1[c] = s1;
  }
}

// lane = edge; weights read wave-uniform (scalar K$ path); no LDS, no barriers
__global__ void __launch_bounds__(256) k_rad3(
    const float* __restrict__ bc,
    const float* __restrict__ w1, const float* __restrict__ b1,
    const float* __restrict__ M0t, const float* __restrict__ M1t,
    const float* __restrict__ bias0, const float* __restrict__ bias1,
    float* __restrict__ q0, bf16* __restrict__ q1b) {
  int gid = blockIdx.x*256 + threadIdx.x;
  int e = gid < E_EDGES ? gid : E_EDGES-1;
  float bcv[8];
  #pragma unroll
  for (int b = 0; b < 8; ++b) bcv[b] = bc[(size_t)e*8 + b];
  float h[64];
  #pragma unroll
  for (int m = 0; m < 64; ++m) {
    float t = b1[m];
    #pragma unroll
    for (int b = 0; b < 8; ++b) t += bcv[b]*w1[b*64 + m];
    h[m] = siluf(t);
  }
  if (gid >= E_EDGES) return;
  for (int c = 0; c < 64; ++c) {
    float a0 = bias0[c], a1 = bias1[c];
    const float* r0 = M0t + c*64;
    const float* r1 = M1t + c*64;
    #pragma unroll
    for (int m = 0; m < 64; ++m) {
      a0 += h[m]*r0[m];
      a1 += h[m]*r1[m];
    }
    q0[(size_t)e*64 + c] = siluf(a0);
    q1b[(size_t)e*64 + c] = __float2bfloat16(siluf(a1));
  }
}

__global__ void k_embed(const float* __restrict__ emb, const int* __restrict__ an,
                        float* __restrict__ node0) {
  int i = blockIdx.x*256 + threadIdx.x;
  int n = i >> 6, c = i & 63;
  node0[i] = emb[an[n]*64 + c];
}

// reorder wnn0_w2[h, off_b + u*m3 + v]  ->  W0r[u*3584 + h*56 + vp]
__global__ void k_w0r(const float* __restrict__ w, float* __restrict__ W0r) {
  int idx = blockIdx.x*256 + threadIdx.x;
  if (idx >= 64*3584) return;
  int u = idx / 3584, r = idx - u*3584;
  int hh = r / 56, vp = r - hh*56;
  int boff, m3, v;
  if (vp < 32)      { boff = 0;    m3 = 32; v = vp; }
  else if (vp < 48) { boff = 2048; m3 = 16; v = vp - 32; }
  else              { boff = 3072; m3 = 8;  v = vp - 48; }
  W0r[idx] = w[hh*3584 + boff + u*m3 + v];
}

// transpose wnn1_w2 (64 x 3456) -> W2t[n][k] bf16
__global__ void k_w2t(const float* __restrict__ w, bf16* __restrict__ W2t) {
  int idx = blockIdx.x*256 + threadIdx.x;   // 221184
  int n = idx >> 6, k = idx & 63;
  W2t[idx] = __float2bfloat16(w[(size_t)k*3456 + n]);
}

// G0[n, h*56+vp] = sum_u node0[n,u] * W0r[u, h*56+vp]
__global__ void __launch_bounds__(256) k_g0(const float* __restrict__ node0,
    const float* __restrict__ W0r, bf16* __restrict__ G0) {
  __shared__ float ns[8][64];
  const int tid = threadIdx.x;
  const int col = blockIdx.x*256 + tid;
  const int nb = blockIdx.y*8;
  for (int i = tid; i < 512; i += 256)
    ns[i>>6][i&63] = node0[(size_t)(nb + (i>>6))*64 + (i&63)];
  __syncthreads();
  float acc[8] = {0,0,0,0,0,0,0,0};
  for (int u = 0; u < 64; ++u) {
    float wv = W0r[(size_t)u*3584 + col];
    #pragma unroll
    for (int n = 0; n < 8; ++n) acc[n] += ns[n][u]*wv;
  }
  #pragma unroll
  for (int n = 0; n < 8; ++n)
    G0[(size_t)(nb+n)*3584 + col] = __float2bfloat16(acc[n]);
}

// layer-0 fused message + aggregate: one wave per edge
__global__ void __launch_bounds__(256) k_msg0(
    const float* __restrict__ q0, const bf16* __restrict__ G0,
    const float* __restrict__ shb, const int* __restrict__ ei,
    float* __restrict__ agg0) {
  const int tid = threadIdx.x;
  const int wave = __builtin_amdgcn_readfirstlane(tid >> 6);
  const int lane = tid & 63;
  const int e = blockIdx.x*4 + wave;
  const int src = ei[e], dst = ei[E_EDGES + e];
  const float* qp = q0 + (size_t)e*64;
  const bf16* gp = G0 + (size_t)src*3584 + lane;
  float z = 0.f;
  if (lane < 56) {
    for (int h = 0; h < 64; ++h) z += qp[h]*b2f(gp[h*56]);
  }
  const float c = 0.125f * 0.3162277660168379f;
  float* ap = agg0 + (size_t)dst*120;
  const float* sh = shb + (size_t)e*12;
  if (lane < 32) {
    atomicAdd(ap + lane, z*c);
  } else if (lane < 48) {
    int v = lane - 32;
    #pragma unroll
    for (int k = 0; k < 3; ++k) atomicAdd(ap + 32 + v*3 + k, z*sh[1+k]*c);
  } else if (lane < 56) {
    int v = lane - 48;
    #pragma unroll
    for (int k = 0; k < 5; ++k) atomicAdd(ap + 80 + v*5 + k, z*sh[4+k]*c);
  }
}

__global__ void k_node1(const float* __restrict__ agg0, const float* __restrict__ node0,
                        const float* __restrict__ sc00, float* __restrict__ node1) {
  __shared__ float n0[64];
  int n = blockIdx.x, tid = threadIdx.x;
  if (tid < 64) n0[tid] = node0[(size_t)n*64 + tid];
  __syncthreads();
  if (tid >= 120) return;
  float v = agg0[(size_t)n*120 + tid];
  if (tid < 32) {
    float s = 0.f;
    for (int u = 0; u < 64; ++u) s += n0[u]*sc00[u*32 + tid];
    v += s * 0.125f;
    v = siluf(v);
  }
  node1[(size_t)n*120 + tid] = v;
}

// ---- layer-1 w-generation GEMM: w[e, n] = sum_k q1b[e,k] * W2t[n,k]  (MFMA bf16)
__global__ void __launch_bounds__(256) k_wgemm(
    const bf16* __restrict__ q1b, const bf16* __restrict__ W2t,
    bf16* __restrict__ wout, int e0, int nE) {
  __shared__ short lds[4][32*64];
  const int tid = threadIdx.x;
  const int wid = tid >> 6, lane = tid & 63;
  const int nt = blockIdx.x*4 + wid;
  const int r0 = blockIdx.y*32;
  const int row16 = lane & 15, quad = lane >> 4;

  short8 a[2][2];
  #pragma unroll
  for (int mi = 0; mi < 2; ++mi) {
    int r = r0 + mi*16 + row16;
    int rg = e0 + ((r < nE) ? r : 0);
    const short* ap = (const short*)q1b + (size_t)rg*64 + quad*8;
    a[mi][0] = *(const short8*)(ap);
    a[mi][1] = *(const short8*)(ap + 32);
  }
  if (nt < 54) {
    f32x4 acc[4][2] = {};
    #pragma unroll
    for (int ni = 0; ni < 4; ++ni) {
      int col = nt*64 + ni*16 + row16;
      const short* bp = (const short*)W2t + (size_t)col*64 + quad*8;
      short8 b0 = *(const short8*)(bp);
      short8 b1 = *(const short8*)(bp + 32);
      #pragma unroll
      for (int mi = 0; mi < 2; ++mi) {
        acc[ni][mi] = __builtin_amdgcn_mfma_f32_16x16x32_bf16(a[mi][0], b0, acc[ni][mi], 0,0,0);
        acc[ni][mi] = __builtin_amdgcn_mfma_f32_16x16x32_bf16(a[mi][1], b1, acc[ni][mi], 0,0,0);
      }
    }
    #pragma unroll
    for (int ni = 0; ni < 4; ++ni)
      #pragma unroll
      for (int mi = 0; mi < 2; ++mi)
        #pragma unroll
        for (int rr = 0; rr < 4; ++rr) {
          bf16 hv = __float2bfloat16(acc[ni][mi][rr]);
          lds[wid][(mi*16 + quad*4 + rr)*64 + ni*16 + row16] = *(short*)&hv;
        }
  }
  __syncthreads();
  if (nt < 54) {
    #pragma unroll
    for (int it = 0; it < 4; ++it) {
      int unit = it*64 + lane;
      int rrow = unit >> 3;
      int cu = (unit & 7) * 8;
      int r = r0 + rrow;
      if (r < nE)
        *(uint4*)((short*)wout + (size_t)r*3456 + nt*64 + cu) =
            *(const uint4*)&lds[wid][rrow*64 + cu];
    }
  }
}

// ---- layer-1 consume: 16 edges/block; w rows read straight from global (L3)
__global__ void __launch_bounds__(256) k_tp2(
    const bf16* __restrict__ wch, const float* __restrict__ node1,
    const float* __restrict__ shb, const int* __restrict__ ei,
    int e0, float* __restrict__ agg1) {
  __shared__ float tv[16][592];
  __shared__ float xs[16][120];
  __shared__ float shs[16][12];
  const int tid = threadIdx.x;
  const int eb = blockIdx.x*16;   // chunk-local first edge

  for (int i = tid; i < 16*120; i += 256) {
    int es = i/120, c = i - es*120;
    int el = eb + es; if (el > WCH-1) el = WCH-1;
    xs[es][c] = node1[(size_t)ei[e0 + el]*120 + c];
  }
  for (int i = tid; i < 16*12; i += 256) {
    int es = i/12, c = i - es*12;
    int el = eb + es; if (el > WCH-1) el = WCH-1;
    shs[es][c] = shb[(size_t)(e0 + el)*12 + c];
  }
  __syncthreads();

  // t tensor: offsets p0:0 p1:32 p2:128 p3:288 p4:336 p5:352 p6:432 p7:480 p8:520 p9:544 p10:552 (592)
  for (int i = tid; i < 16*592; i += 256) {
    int es = i / 592; int idx = i - es*592;
    const float* x  = xs[es];
    const float* sh = shs[es];
    float t = 0.0f; int p;
    if (idx < 32)       { p = 0; int u = idx;            t = x[u]; }
    else if (idx < 128) { p = 1; int j = idx-32,  u=j/3, k=j-u*3; t = x[u]*sh[1+k]; }
    else if (idx < 288) { p = 2; int j = idx-128, u=j/5, k=j-u*5; t = x[u]*sh[4+k]; }
    else if (idx < 336) { p = 3; int j = idx-288, u=j/3, k=j-u*3; t = x[32+u*3+k]; }
    else if (idx < 352) { p = 4; int u = idx-336;
      t = x[32+u*3]*sh[1] + x[32+u*3+1]*sh[2] + x[32+u*3+2]*sh[3]; }
    else if (idx < 432) { p = 5; int j = idx-352, u=j/5, k=j-u*5;
      for (int q = 0; q < 11; ++q) if (C112_K[q] == k)
        t += C112_V[q]*x[32+u*3+C112_I[q]]*sh[1+C112_J[q]]; }
    else if (idx < 480) { p = 6; int j = idx-432, u=j/3, k=j-u*3;
      for (int q = 0; q < 11; ++q) if (C112_J[q] == k)
        t += C112_V[q]*x[32+u*3+C112_I[q]]*sh[4+C112_K[q]]; }
    else if (idx < 520) { p = 7; int j = idx-480, u=j/5, k=j-u*5; t = x[80+u*5+k]; }
    else if (idx < 544) { p = 8; int j = idx-520, u=j/3, k=j-u*3;
      for (int q = 0; q < 11; ++q) if (C112_J[q] == k)
        t += C112_V[q]*x[80+u*5+C112_K[q]]*sh[1+C112_I[q]]; }
    else if (idx < 552) { p = 9; int u = idx-544;
      for (int q = 0; q < 5; ++q) t += x[80+u*5+q]*sh[4+q]; }
    else                { p = 10; int j = idx-552, u=j/5, k=j-u*5;
      for (int q = 0; q < 25; ++q) if (C222_K[q] == k)
        t += C222_V[q]*x[80+u*5+C222_I[q]]*sh[4+C222_J[q]]; }
    tv[es][idx] = t * P_SC_[p];
  }
  __syncthreads();

  for (int i = tid; i < 16*120; i += 256) {
    int es = i/120, c = i - es*120;
    int el = eb + es;
    if (el >= WCH) continue;
    const bf16* w = wch + (size_t)el*3456;
    const float* t = tv[es];
    float acc = 0.f;
    if (c < 32) {
      for (int u = 0; u < 32; ++u) acc += b2f(w[u*32+c])      * t[u];
      for (int u = 0; u < 16; ++u) acc += b2f(w[2048+u*32+c]) * t[336+u];
      for (int u = 0; u <  8; ++u) acc += b2f(w[3136+u*32+c]) * t[544+u];
    } else if (c < 80) {
      int j = c-32, v = j/3, k = j-v*3;
      for (int u = 0; u < 32; ++u) acc += b2f(w[1024+u*16+v]) * t[32+u*3+k];
      for (int u = 0; u < 16; ++u) acc += b2f(w[1792+u*16+v]) * t[288+u*3+k];
      for (int u = 0; u < 16; ++u) acc += b2f(w[2688+u*16+v]) * t[432+u*3+k];
      for (int u = 0; u <  8; ++u) acc += b2f(w[3008+u*16+v]) * t[520+u*3+k];
    } else {
      int j = c-80, v = j/5, k = j-v*5;
      for (int u = 0; u < 32; ++u) acc += b2f(w[1536+u*8+v])  * t[128+u*5+k];
      for (int u = 0; u < 16; ++u) acc += b2f(w[2560+u*8+v])  * t[352+u*5+k];
      for (int u = 0; u <  8; ++u) acc += b2f(w[2944+u*8+v])  * t[480+u*5+k];
      for (int u = 0; u <  8; ++u) acc += b2f(w[3392+u*8+v])  * t[552+u*5+k];
    }
    int dst = ei[E_EDGES + e0 + el];
    atomicAdd(&agg1[(size_t)dst*120 + c], acc * 0.3162277660168379f);
  }
}

__global__ void k_out(const float* __restrict__ agg1, const float* __restrict__ node1,
                      const float* __restrict__ sc0e, const float* __restrict__ sc1o,
                      const float* __restrict__ sc2e, float* __restrict__ out) {
  __shared__ float x[120];
  int n = blockIdx.x, tid = threadIdx.x;
  if (tid < 120) x[tid] = node1[(size_t)n*120 + tid];
  __syncthreads();
  if (tid >= 120) return;
  float v = agg1[(size_t)n*120 + tid];
  if (tid < 32) {
    float s = 0.f;
    for (int u = 0; u < 32; ++u) s += x[u]*sc0e[u*32 + tid];
    v += s * 0.1767766952966369f;
  } else if (tid < 80) {
    int jj = tid - 32, vv = jj/3, k = jj - vv*3;
    float s = 0.f;
    for (int u = 0; u < 16; ++u) s += x[32 + u*3 + k]*sc1o[u*16 + vv];
    v += s * 0.25f;
  } else {
    int jj = tid - 80, vv = jj/5, k = jj - vv*5;
    float s = 0.f;
    for (int u = 0; u < 8; ++u) s += x[80 + u*5 + k]*sc2e[u*8 + vv];
    v += s * 0.3535533905932738f;
  }
  out[(size_t)n*120 + tid] = v;
}

// ---------------- launch ----------------
extern "C" void kernel_launch(void* const* d_in, const int* in_sizes, int n_in,
                              void* d_out, int out_size, void* d_ws, size_t ws_size,
                              hipStream_t stream) {
  const float* embed   = (const float*)d_in[1];
  const float* rad_w1  = (const float*)d_in[2];
  const float* rad_b1  = (const float*)d_in[3];
  const float* rad_w2  = (const float*)d_in[4];
  const float* rad_b2  = (const float*)d_in[5];
  const float* wnn0_w1 = (const float*)d_in[6];
  const float* wnn0_w2 = (const float*)d_in[7];
  const float* wnn1_w1 = (const float*)d_in[8];
  const float* wnn1_w2 = (const float*)d_in[9];
  const float* sc0_0e  = (const float*)d_in[10];
  const float* sc1_0e  = (const float*)d_in[11];
  const float* sc1_1o  = (const float*)d_in[12];
  const float* sc1_2e  = (const float*)d_in[13];
  const float* edge_vec = (const float*)d_in[14];
  const float* edge_len = (const float*)d_in[15];
  const int*  anum    = (const int*)d_in[16];
  const int*  ei      = (const int*)d_in[17];

  float* ws = (float*)d_ws;
  float* shbuf = ws;                      // 600000
  float* bc    = ws + 600000;             // 400000
  bf16*  q1b   = (bf16*)(ws + 1000000);   // 3.2M bf16 = 1.6M f-slots
  float* node0 = ws + 2600000;            // 320000
  float* W0r   = ws + 2920000;            // 229376
  bf16*  W2t   = (bf16*)(ws + 3149376);   // 221184 bf16 = 110592 f-slots
  float* M0t   = ws + 3259968;            // 4096
  float* M1t   = ws + 3264064;            // 4096
  float* bias0 = ws + 3268160;            // 64
  float* bias1 = ws + 3268224;            // 64
  float* agg0  = ws + 3268288;            // 600000
  float* node1 = ws + 3868288;            // 600000
  float* agg1  = ws + 4468288;            // 600000
  float* q0    = ws + 5068288;            // 3200000
  bf16*  G0    = (bf16*)(ws + 8268288);   // 8.96M f-slots -> end 17228288 (68.9 MB)
  bf16*  wchunk = (bf16*)(ws + 5068288);  // aliases q0+G0 (dead by layer-1)

  hipMemsetAsync(agg0, 0, 600000*sizeof(float), stream);
  hipMemsetAsync(agg1, 0, 600000*sizeof(float), stream);

  k_prep<<<(E_EDGES+255)/256, 256, 0, stream>>>(edge_vec, edge_len, shbuf, bc);
  k_fuse<<<16, 256, 0, stream>>>(rad_w2, rad_b2, wnn0_w1, wnn1_w1, M0t, M1t, bias0, bias1);
  k_rad3<<<(E_EDGES+255)/256, 256, 0, stream>>>(bc, rad_w1, rad_b1, M0t, M1t,
                                                bias0, bias1, q0, q1b);
  k_embed<<<(NN*64)/256, 256, 0, stream>>>(embed, anum, node0);
  k_w0r<<<(64*3584+255)/256, 256, 0, stream>>>(wnn0_w2, W0r);
  k_w2t<<<(64*3456)/256, 256, 0, stream>>>(wnn1_w2, W2t);
  k_g0<<<dim3(14, NN/8), 256, 0, stream>>>(node0, W0r, G0);
  k_msg0<<<E_EDGES/4, 256, 0, stream>>>(q0, G0, shbuf, ei, agg0);
  k_node1<<<NN, 128, 0, stream>>>(agg0, node0, sc0_0e, node1);

  for (int c = 0; c < 8; ++c) {
    int e0 = c * WCH;
    k_wgemm<<<dim3(14, (WCH+31)/32), 256, 0, stream>>>(q1b, W2t, wchunk, e0, WCH);
    k_tp2<<<(WCH+15)/16, 256, 0, stream>>>(wchunk, node1, shbuf, ei, e0, agg1);
  }
  k_out<<<NN, 128, 0, stream>>>(agg1, node1, sc1_0e, sc1_1o, sc1_2e, (float*)d_out);
}

// Round 6
// 1082.758 us; speedup vs baseline: 1.1520x; 1.1520x over previous
//
#include <hip/hip_runtime.h>
#include <hip/hip_bf16.h>
#include <math.h>

#define E_EDGES 50000
#define NN 5000

typedef __hip_bfloat16 bf16;
typedef __attribute__((ext_vector_type(8))) short short8;
typedef __attribute__((ext_vector_type(4))) float f32x4;

__device__ __forceinline__ float b2f(bf16 v) { return __bfloat162float(v); }
__device__ __forceinline__ float siluf(float x) { return x / (1.0f + __expf(-x)); }
__device__ __forceinline__ float us2f(unsigned short u) {
  union { unsigned int i; float f; } c; c.i = ((unsigned int)u) << 16; return c.f;
}

// ---------------- CG / path constant tables ----------------
__constant__ int   C112_I[11] = {0,2,0,1,1,2, 0,1,2, 0,2};
__constant__ int   C112_J[11] = {2,0,1,0,2,1, 0,1,2, 0,2};
__constant__ int   C112_K[11] = {0,0,1,1,3,3, 2,2,2, 4,4};
__constant__ float C112_V[11] = {
  0.3162277660168379f, 0.3162277660168379f, 0.3162277660168379f,
  0.3162277660168379f, 0.3162277660168379f, 0.3162277660168379f,
 -0.1825741858350554f, 0.3651483716701107f,-0.1825741858350554f,
 -0.3162277660168379f, 0.3162277660168379f};

__constant__ int   C222_I[25] = {0,0,2, 0,0,1,1,3,3, 1,1,2, 1,1,4, 2, 2,3,3, 2,4,4, 3,3,4};
__constant__ int   C222_J[25] = {0,2,0, 1,3,0,3,0,1, 1,2,1, 1,4,1, 2, 3,2,3, 4,2,4, 3,4,3};
__constant__ int   C222_K[25] = {2,0,0, 3,1,3,0,1,0, 2,1,1, 4,1,1, 2, 3,3,2, 4,4,2, 4,3,3};
__constant__ float C222_V[25] = {
  0.2390457218668787f, 0.2390457218668787f, 0.2390457218668787f,
 -0.2070196678027063f,-0.2070196678027063f,-0.2070196678027063f,
 -0.2070196678027063f,-0.2070196678027063f,-0.2070196678027063f,
 -0.1195228609334394f,-0.1195228609334394f,-0.1195228609334394f,
  0.2070196678027063f, 0.2070196678027063f, 0.2070196678027063f,
 -0.2390457218668787f,
 -0.1195228609334394f,-0.1195228609334394f,-0.1195228609334394f,
  0.2390457218668787f, 0.2390457218668787f, 0.2390457218668787f,
 -0.2070196678027063f,-0.2070196678027063f,-0.2070196678027063f};

// per-path scale (alpha, diag-CG folded)
__constant__ float P_SC_[11] = {
  0.1336306209562122f, 0.1178511301977579f, 0.125f, 0.1178511301977579f,
  0.0771516749810460f, 0.2795084971874737f, 0.2041241452319315f, 0.125f,
  0.2041241452319315f, 0.0597614304667197f, 0.2795084971874737f};

// layer-1 path tables
__constant__ int OFFE_[12] = {0,1024,1536,1792,2048,2560,2688,2944,3008,3136,3392,3456};
__constant__ int M1__[11]  = {32,32,32,16,16,16,16, 8, 8, 8, 8};
__constant__ int M3__[11]  = {32,16, 8,16,32, 8,16, 8,16,32, 8};
__constant__ int TS_[11]   = {0,64,96,112,128,160,168,184,188,196,212};  // 16-col tile starts
__constant__ int NK_[11]   = {1,3,5,3,1,5,3,5,3,1,5};
__constant__ int MOFF_[11] = {0,32,80,32,0,80,32,80,32,0,80};
__constant__ int TOFF_[11] = {0,32,128,288,336,352,432,480,520,544,552};

// ---------------- kernels ----------------

__global__ void k_prep(const float* __restrict__ evec, const float* __restrict__ elen,
                       float* __restrict__ shb, float* __restrict__ bc) {
  int e = blockIdx.x * 256 + threadIdx.x;
  if (e >= E_EDGES) return;
  float x = evec[3*e+0], y = evec[3*e+1], z = evec[3*e+2];
  float r = elen[e];
  float inv = 1.0f / (r + 1e-8f);
  float ux = x*inv, uy = y*inv, uz = z*inv;
  const float s3 = 1.7320508075688772f, s5 = 2.2360679774997896f, s15 = 3.8729833462074170f;
  float* sh = shb + (size_t)e*12;
  sh[0] = 1.0f;
  sh[1] = s3*uy; sh[2] = s3*uz; sh[3] = s3*ux;
  sh[4] = s15*ux*uy; sh[5] = s15*uy*uz; sh[6] = 0.5f*s5*(3.0f*uz*uz - 1.0f);
  sh[7] = s15*ux*uz; sh[8] = 0.5f*s15*(ux*ux - uy*uy);
  sh[9] = 0.f; sh[10] = 0.f; sh[11] = 0.f;
  float rr = fmaxf(r, 1e-8f);
  const float pi = 3.14159265358979f;
  float xr = r * 0.2f;
  float cut = (xr < 1.0f) ? 0.5f*(1.0f + cosf(pi*xr)) : 0.0f;
  float fb = pi * 0.2f;
  for (int k = 1; k <= 8; ++k)
    bc[(size_t)e*8 + (k-1)] = sinf(fb*(float)k*r)/rr * cut;
}

// fold rad_w2 into wnn*_w1: M0[hh*64+c] = sum_j rad_w2[hh][j] * wnn0_w1[j][c]
__global__ void k_fuse(const float* __restrict__ w2, const float* __restrict__ b2,
                       const float* __restrict__ w01, const float* __restrict__ w11,
                       float* __restrict__ M0, float* __restrict__ M1,
                       float* __restrict__ bias0, float* __restrict__ bias1) {
  int i = blockIdx.x*256 + threadIdx.x;   // 4096
  int hh = i >> 6, c = i & 63;
  float a0 = 0.f, a1 = 0.f;
  for (int j = 0; j < 64; ++j) {
    float wv = w2[hh*64 + j];
    a0 += wv * w01[j*64 + c];
    a1 += wv * w11[j*64 + c];
  }
  M0[hh*64 + c] = a0;
  M1[hh*64 + c] = a1;
  if (hh == 0) {
    float s0 = 0.f, s1 = 0.f;
    for (int j = 0; j < 64; ++j) {
      s0 += b2[j] * w01[j*64 + c];
      s1 += b2[j] * w11[j*64 + c];
    }
    bias0[c] = s0;
    bias1[c] = s1;
  }
}

// 32 edges/block; fused weights staged in LDS; lane=channel -> coalesced writes
__global__ void __launch_bounds__(256) k_rad4(
    const float* __restrict__ bc,
    const float* __restrict__ w1, const float* __restrict__ b1,
    const float* __restrict__ M0, const float* __restrict__ M1,
    const float* __restrict__ bias0, const float* __restrict__ bias1,
    float* __restrict__ q0, bf16* __restrict__ q1b) {
  __shared__ float sM0[4096], sM1[4096], sW1[512];
  __shared__ float sB[64], sb0[64], sb1[64];
  __shared__ float sH[4][64], sBC[4][8];
  const int tid = threadIdx.x;
  const int j = tid >> 6, m = tid & 63;
  for (int i = tid; i < 4096; i += 256) { sM0[i] = M0[i]; sM1[i] = M1[i]; }
  for (int i = tid; i < 512; i += 256) sW1[i] = w1[i];
  if (tid < 64) { sB[tid] = b1[tid]; sb0[tid] = bias0[tid]; sb1[tid] = bias1[tid]; }
  __syncthreads();
  for (int g = 0; g < 8; ++g) {
    int e = blockIdx.x*32 + g*4 + j;
    int eL = e < E_EDGES ? e : E_EDGES-1;
    if (m < 8) sBC[j][m] = bc[(size_t)eL*8 + m];   // intra-wave LDS dep: safe
    float t = sB[m];
    #pragma unroll
    for (int b = 0; b < 8; ++b) t += sBC[j][b]*sW1[b*64 + m];
    sH[j][m] = siluf(t);
    float a0 = sb0[m], a1 = sb1[m];
    for (int mm = 0; mm < 64; ++mm) {
      float hv = sH[j][mm];
      a0 += hv*sM0[mm*64 + m];
      a1 += hv*sM1[mm*64 + m];
    }
    if (e < E_EDGES) {
      q0[(size_t)e*64 + m] = siluf(a0);
      q1b[(size_t)e*64 + m] = __float2bfloat16(siluf(a1));
    }
  }
}

__global__ void k_embed(const float* __restrict__ emb, const int* __restrict__ an,
                        float* __restrict__ node0) {
  int i = blockIdx.x*256 + threadIdx.x;
  int n = i >> 6, c = i & 63;
  node0[i] = emb[an[n]*64 + c];
}

// reorder wnn0_w2[h, off_b + u*m3 + v] -> W0r[u*3584 + vp*64 + h]  (h-contiguous)
__global__ void k_w0r(const float* __restrict__ w, float* __restrict__ W0r) {
  int idx = blockIdx.x*256 + threadIdx.x;
  if (idx >= 64*3584) return;
  int u = idx / 3584, r = idx - u*3584;
  int vp = r >> 6, hh = r & 63;
  int boff, m3, v;
  if (vp < 32)      { boff = 0;    m3 = 32; v = vp; }
  else if (vp < 48) { boff = 2048; m3 = 16; v = vp - 32; }
  else              { boff = 3072; m3 = 8;  v = vp - 48; }
  W0r[idx] = w[hh*3584 + boff + u*m3 + v];
}

// wnn1_w2 (64 x 3456) -> W2t[nn][k] bf16, columns permuted to [v][u] inside each path
__global__ void k_w2tp(const float* __restrict__ w, bf16* __restrict__ W2t) {
  int idx = blockIdx.x*256 + threadIdx.x;   // 221184
  int nn = idx >> 6, k = idx & 63;
  int p = 0;
  for (int pp = 1; pp < 11; ++pp) if (nn >= OFFE_[pp]) p = pp;
  int local = nn - OFFE_[p];
  int m1 = M1__[p], m3 = M3__[p];
  int v = local / m1, u = local - v*m1;
  W2t[idx] = __float2bfloat16(w[(size_t)k*3456 + OFFE_[p] + u*m3 + v]);
}

// G0[n, vp*64+h] = sum_u node0[n,u] * W0r[u, vp*64+h]
__global__ void __launch_bounds__(256) k_g0(const float* __restrict__ node0,
    const float* __restrict__ W0r, bf16* __restrict__ G0) {
  __shared__ float ns[8][64];
  const int tid = threadIdx.x;
  const int col = blockIdx.x*256 + tid;
  const int nb = blockIdx.y*8;
  for (int i = tid; i < 512; i += 256)
    ns[i>>6][i&63] = node0[(size_t)(nb + (i>>6))*64 + (i&63)];
  __syncthreads();
  float acc[8] = {0,0,0,0,0,0,0,0};
  for (int u = 0; u < 64; ++u) {
    float wv = W0r[(size_t)u*3584 + col];
    #pragma unroll
    for (int n = 0; n < 8; ++n) acc[n] += ns[n][u]*wv;
  }
  #pragma unroll
  for (int n = 0; n < 8; ++n)
    G0[(size_t)(nb+n)*3584 + col] = __float2bfloat16(acc[n]);
}

// layer-0 message + aggregate: one wave per edge; vectorized G0 reads
__global__ void __launch_bounds__(256) k_msg0(
    const float* __restrict__ q0, const bf16* __restrict__ G0,
    const float* __restrict__ shb, const int* __restrict__ ei,
    float* __restrict__ agg0) {
  __shared__ float sq[4][64];
  const int tid = threadIdx.x;
  const int wave = tid >> 6;
  const int lane = tid & 63;
  const int e = blockIdx.x*4 + wave;
  for (int i = tid; i < 256; i += 256)
    sq[i>>6][i&63] = q0[(size_t)(blockIdx.x*4 + (i>>6))*64 + (i&63)];
  __syncthreads();
  const int src = ei[e], dst = ei[E_EDGES + e];
  float z = 0.f;
  if (lane < 56) {
    const short* gp = (const short*)G0 + (size_t)src*3584 + lane*64;
    #pragma unroll
    for (int hb = 0; hb < 8; ++hb) {
      short8 g = *(const short8*)(gp + hb*8);
      #pragma unroll
      for (int jj = 0; jj < 8; ++jj)
        z += sq[wave][hb*8+jj]*us2f((unsigned short)g[jj]);
    }
  }
  const float c = 0.125f * 0.3162277660168379f;
  float* ap = agg0 + (size_t)dst*120;
  const float* sh = shb + (size_t)e*12;
  if (lane < 32) {
    atomicAdd(ap + lane, z*c);
  } else if (lane < 48) {
    int v = lane - 32;
    #pragma unroll
    for (int k = 0; k < 3; ++k) atomicAdd(ap + 32 + v*3 + k, z*sh[1+k]*c);
  } else if (lane < 56) {
    int v = lane - 48;
    #pragma unroll
    for (int k = 0; k < 5; ++k) atomicAdd(ap + 80 + v*5 + k, z*sh[4+k]*c);
  }
}

__global__ void k_node1(const float* __restrict__ agg0, const float* __restrict__ node0,
                        const float* __restrict__ sc00, float* __restrict__ node1) {
  __shared__ float n0[64];
  int n = blockIdx.x, tid = threadIdx.x;
  if (tid < 64) n0[tid] = node0[(size_t)n*64 + tid];
  __syncthreads();
  if (tid >= 120) return;
  float v = agg0[(size_t)n*120 + tid];
  if (tid < 32) {
    float s = 0.f;
    for (int u = 0; u < 64; ++u) s += n0[u]*sc00[u*32 + tid];
    v += s * 0.125f;
    v = siluf(v);
  }
  node1[(size_t)n*120 + tid] = v;
}

// ---- fused layer-1: per block 16 edges; MFMA w-tiles (A=W2t, B=q -> C rows=u, cols=edge),
// consume immediately via in-reg partial + shfl_xor reduce; w never materialized.
__global__ void __launch_bounds__(256) k_tpf(
    const bf16* __restrict__ q1b, const bf16* __restrict__ W2t,
    const float* __restrict__ node1, const float* __restrict__ shb,
    const int* __restrict__ ei, float* __restrict__ agg1) {
  __shared__ float tv[16*593];      // t tensor, stride 593 (conflict-free)
  __shared__ float msg[16*120];
  __shared__ float xs[16][120];
  __shared__ float shs[16][12];
  const int tid = threadIdx.x;
  const int e0 = blockIdx.x * 16;
  const int lane = tid & 63;
  const int wv = tid >> 6;
  const int row16 = lane & 15, quad = lane >> 4;

  for (int i = tid; i < 16*120; i += 256) {
    int es = i/120, c = i - es*120;
    xs[es][c] = node1[(size_t)ei[e0 + es]*120 + c];
    msg[i] = 0.f;
  }
  for (int i = tid; i < 192; i += 256) {
    int es = i/12, c = i - es*12;
    shs[es][c] = shb[(size_t)(e0+es)*12 + c];
  }
  // B-frag: q rows for this block's 16 edges (B[k][n=edge])
  const short* qp = (const short*)q1b + (size_t)(e0 + row16)*64 + quad*8;
  short8 bq0 = *(const short8*)qp;
  short8 bq1 = *(const short8*)(qp + 32);
  __syncthreads();

  // build t (offsets p0:0 p1:32 p2:128 p3:288 p4:336 p5:352 p6:432 p7:480 p8:520 p9:544 p10:552)
  for (int i = tid; i < 16*592; i += 256) {
    int es = i / 592; int idx = i - es*592;
    const float* x  = xs[es];
    const float* sh = shs[es];
    float t = 0.0f; int p;
    if (idx < 32)       { p = 0; int u = idx;            t = x[u]; }
    else if (idx < 128) { p = 1; int j = idx-32,  u=j/3, k=j-u*3; t = x[u]*sh[1+k]; }
    else if (idx < 288) { p = 2; int j = idx-128, u=j/5, k=j-u*5; t = x[u]*sh[4+k]; }
    else if (idx < 336) { p = 3; int j = idx-288, u=j/3, k=j-u*3; t = x[32+u*3+k]; }
    else if (idx < 352) { p = 4; int u = idx-336;
      t = x[32+u*3]*sh[1] + x[32+u*3+1]*sh[2] + x[32+u*3+2]*sh[3]; }
    else if (idx < 432) { p = 5; int j = idx-352, u=j/5, k=j-u*5;
      for (int q = 0; q < 11; ++q) if (C112_K[q] == k)
        t += C112_V[q]*x[32+u*3+C112_I[q]]*sh[1+C112_J[q]]; }
    else if (idx < 480) { p = 6; int j = idx-432, u=j/3, k=j-u*3;
      for (int q = 0; q < 11; ++q) if (C112_J[q] == k)
        t += C112_V[q]*x[32+u*3+C112_I[q]]*sh[4+C112_K[q]]; }
    else if (idx < 520) { p = 7; int j = idx-480, u=j/5, k=j-u*5; t = x[80+u*5+k]; }
    else if (idx < 544) { p = 8; int j = idx-520, u=j/3, k=j-u*3;
      for (int q = 0; q < 11; ++q) if (C112_J[q] == k)
        t += C112_V[q]*x[80+u*5+C112_K[q]]*sh[1+C112_I[q]]; }
    else if (idx < 552) { p = 9; int u = idx-544;
      for (int q = 0; q < 5; ++q) t += x[80+u*5+q]*sh[4+q]; }
    else                { p = 10; int j = idx-552, u=j/5, k=j-u*5;
      for (int q = 0; q < 25; ++q) if (C222_K[q] == k)
        t += C222_V[q]*x[80+u*5+C222_I[q]]*sh[4+C222_J[q]]; }
    tv[es*593 + idx] = t * P_SC_[p];
  }
  __syncthreads();

  for (int t16 = wv; t16 < 216; t16 += 4) {
    int p = 0;
    #pragma unroll
    for (int pp = 1; pp < 11; ++pp) if (t16 >= TS_[pp]) p = pp;
    int lt = t16 - TS_[p];
    int u0, v0;
    if (p < 3)      { v0 = lt >> 1; u0 = (lt & 1) * 16; }
    else if (p < 7) { v0 = lt; u0 = 0; }
    else            { v0 = lt*2; u0 = 0; }
    const int nk = NK_[p], moff = MOFF_[p], toff = TOFF_[p];

    const short* ap = (const short*)W2t + (size_t)(t16*16 + row16)*64 + quad*8;
    short8 a0 = *(const short8*)ap;
    short8 a1 = *(const short8*)(ap + 32);
    f32x4 acc = {0.f,0.f,0.f,0.f};
    acc = __builtin_amdgcn_mfma_f32_16x16x32_bf16(a0, bq0, acc, 0,0,0);
    acc = __builtin_amdgcn_mfma_f32_16x16x32_bf16(a1, bq1, acc, 0,0,0);
    // lane holds w[e=row16][u-index = quad*4+r] in acc[r]
    const float* te = tv + row16*593 + toff;
    for (int k = 0; k < nk; ++k) {
      float s = 0.f;
      #pragma unroll
      for (int r = 0; r < 4; ++r) {
        int u = (p < 7) ? (u0 + quad*4 + r) : ((quad*4 + r) & 7);
        s += acc[r] * te[u*nk + k];
      }
      s += __shfl_xor(s, 16);
      if (p < 7) {
        s += __shfl_xor(s, 32);
        if (quad == 0) atomicAdd(&msg[row16*120 + moff + v0*nk + k], s);
      } else {
        if (quad == 0)      atomicAdd(&msg[row16*120 + moff + v0*nk + k], s);
        else if (quad == 2) atomicAdd(&msg[row16*120 + moff + (v0+1)*nk + k], s);
      }
    }
  }
  __syncthreads();
  for (int i = tid; i < 16*120; i += 256) {
    int es = i/120, c = i - es*120;
    atomicAdd(&agg1[(size_t)ei[E_EDGES + e0 + es]*120 + c], msg[i]*0.3162277660168379f);
  }
}

__global__ void k_out(const float* __restrict__ agg1, const float* __restrict__ node1,
                      const float* __restrict__ sc0e, const float* __restrict__ sc1o,
                      const float* __restrict__ sc2e, float* __restrict__ out) {
  __shared__ float x[120];
  int n = blockIdx.x, tid = threadIdx.x;
  if (tid < 120) x[tid] = node1[(size_t)n*120 + tid];
  __syncthreads();
  if (tid >= 120) return;
  float v = agg1[(size_t)n*120 + tid];
  if (tid < 32) {
    float s = 0.f;
    for (int u = 0; u < 32; ++u) s += x[u]*sc0e[u*32 + tid];
    v += s * 0.1767766952966369f;
  } else if (tid < 80) {
    int jj = tid - 32, vv = jj/3, k = jj - vv*3;
    float s = 0.f;
    for (int u = 0; u < 16; ++u) s += x[32 + u*3 + k]*sc1o[u*16 + vv];
    v += s * 0.25f;
  } else {
    int jj = tid - 80, vv = jj/5, k = jj - vv*5;
    float s = 0.f;
    for (int u = 0; u < 8; ++u) s += x[80 + u*5 + k]*sc2e[u*8 + vv];
    v += s * 0.3535533905932738f;
  }
  out[(size_t)n*120 + tid] = v;
}

// ---------------- launch ----------------
extern "C" void kernel_launch(void* const* d_in, const int* in_sizes, int n_in,
                              void* d_out, int out_size, void* d_ws, size_t ws_size,
                              hipStream_t stream) {
  const float* embed   = (const float*)d_in[1];
  const float* rad_w1  = (const float*)d_in[2];
  const float* rad_b1  = (const float*)d_in[3];
  const float* rad_w2  = (const float*)d_in[4];
  const float* rad_b2  = (const float*)d_in[5];
  const float* wnn0_w1 = (const float*)d_in[6];
  const float* wnn0_w2 = (const float*)d_in[7];
  const float* wnn1_w1 = (const float*)d_in[8];
  const float* wnn1_w2 = (const float*)d_in[9];
  const float* sc0_0e  = (const float*)d_in[10];
  const float* sc1_0e  = (const float*)d_in[11];
  const float* sc1_1o  = (const float*)d_in[12];
  const float* sc1_2e  = (const float*)d_in[13];
  const float* edge_vec = (const float*)d_in[14];
  const float* edge_len = (const float*)d_in[15];
  const int*  anum    = (const int*)d_in[16];
  const int*  ei      = (const int*)d_in[17];

  float* ws = (float*)d_ws;
  float* shbuf = ws;                      // 600000
  float* bc    = ws + 600000;             // 400000
  bf16*  q1b   = (bf16*)(ws + 1000000);   // 1.6M f-slots
  float* node0 = ws + 2600000;            // 320000
  float* W0r   = ws + 2920000;            // 229376
  bf16*  W2t   = (bf16*)(ws + 3149376);   // 110592 f-slots
  float* M0    = ws + 3259968;            // 4096
  float* M1    = ws + 3264064;            // 4096
  float* bias0 = ws + 3268160;            // 64
  float* bias1 = ws + 3268224;            // 64
  float* agg0  = ws + 3268288;            // 600000
  float* node1 = ws + 3868288;            // 600000
  float* agg1  = ws + 4468288;            // 600000
  float* q0    = ws + 5068288;            // 3200000
  bf16*  G0    = (bf16*)(ws + 8268288);   // 8.96M f-slots -> end 17228288 (68.9 MB)

  hipMemsetAsync(agg0, 0, 600000*sizeof(float), stream);
  hipMemsetAsync(agg1, 0, 600000*sizeof(float), stream);

  k_prep<<<(E_EDGES+255)/256, 256, 0, stream>>>(edge_vec, edge_len, shbuf, bc);
  k_fuse<<<16, 256, 0, stream>>>(rad_w2, rad_b2, wnn0_w1, wnn1_w1, M0, M1, bias0, bias1);
  k_rad4<<<(E_EDGES+31)/32, 256, 0, stream>>>(bc, rad_w1, rad_b1, M0, M1,
                                              bias0, bias1, q0, q1b);
  k_embed<<<(NN*64)/256, 256, 0, stream>>>(embed, anum, node0);
  k_w0r<<<(64*3584+255)/256, 256, 0, stream>>>(wnn0_w2, W0r);
  k_w2tp<<<(64*3456)/256, 256, 0, stream>>>(wnn1_w2, W2t);
  k_g0<<<dim3(14, NN/8), 256, 0, stream>>>(node0, W0r, G0);
  k_msg0<<<E_EDGES/4, 256, 0, stream>>>(q0, G0, shbuf, ei, agg0);
  k_node1<<<NN, 128, 0, stream>>>(agg0, node0, sc0_0e, node1);
  k_tpf<<<E_EDGES/16, 256, 0, stream>>>(q1b, W2t, node1, shbuf, ei, agg1);
  k_out<<<NN, 128, 0, stream>>>(agg1, node1, sc1_0e, sc1_1o, sc1_2e, (float*)d_out);
}

// Round 7
// 821.519 us; speedup vs baseline: 1.5184x; 1.3180x over previous
//
#include <hip/hip_runtime.h>
#include <hip/hip_bf16.h>
#include <math.h>

#define E_EDGES 50000
#define NN 5000
#define WCH 6250          // edges per layer-1 w chunk (8 chunks)

typedef __hip_bfloat16 bf16;
typedef __attribute__((ext_vector_type(8))) short short8;
typedef __attribute__((ext_vector_type(4))) float f32x4;

__device__ __forceinline__ float b2f(bf16 v) { return __bfloat162float(v); }
__device__ __forceinline__ float siluf(float x) { return x / (1.0f + __expf(-x)); }
__device__ __forceinline__ float us2f(unsigned short u) {
  union { unsigned int i; float f; } c; c.i = ((unsigned int)u) << 16; return c.f;
}

// ---------------- kernels ----------------

__global__ void k_prep(const float* __restrict__ evec, const float* __restrict__ elen,
                       float* __restrict__ shb, float* __restrict__ bc) {
  int e = blockIdx.x * 256 + threadIdx.x;
  if (e >= E_EDGES) return;
  float x = evec[3*e+0], y = evec[3*e+1], z = evec[3*e+2];
  float r = elen[e];
  float inv = 1.0f / (r + 1e-8f);
  float ux = x*inv, uy = y*inv, uz = z*inv;
  const float s3 = 1.7320508075688772f, s5 = 2.2360679774997896f, s15 = 3.8729833462074170f;
  float* sh = shb + (size_t)e*12;
  sh[0] = 1.0f;
  sh[1] = s3*uy; sh[2] = s3*uz; sh[3] = s3*ux;
  sh[4] = s15*ux*uy; sh[5] = s15*uy*uz; sh[6] = 0.5f*s5*(3.0f*uz*uz - 1.0f);
  sh[7] = s15*ux*uz; sh[8] = 0.5f*s15*(ux*ux - uy*uy);
  sh[9] = 0.f; sh[10] = 0.f; sh[11] = 0.f;
  float rr = fmaxf(r, 1e-8f);
  const float pi = 3.14159265358979f;
  float xr = r * 0.2f;
  float cut = (xr < 1.0f) ? 0.5f*(1.0f + cosf(pi*xr)) : 0.0f;
  float fb = pi * 0.2f;
  for (int k = 1; k <= 8; ++k)
    bc[(size_t)e*8 + (k-1)] = sinf(fb*(float)k*r)/rr * cut;
}

// fold rad_w2 into wnn*_w1: M0[hh*64+c] = sum_j rad_w2[hh][j] * wnn0_w1[j][c]
__global__ void k_fuse(const float* __restrict__ w2, const float* __restrict__ b2,
                       const float* __restrict__ w01, const float* __restrict__ w11,
                       float* __restrict__ M0, float* __restrict__ M1,
                       float* __restrict__ bias0, float* __restrict__ bias1) {
  int i = blockIdx.x*256 + threadIdx.x;   // 4096
  int hh = i >> 6, c = i & 63;
  float a0 = 0.f, a1 = 0.f;
  for (int j = 0; j < 64; ++j) {
    float wv = w2[hh*64 + j];
    a0 += wv * w01[j*64 + c];
    a1 += wv * w11[j*64 + c];
  }
  M0[hh*64 + c] = a0;
  M1[hh*64 + c] = a1;
  if (hh == 0) {
    float s0 = 0.f, s1 = 0.f;
    for (int j = 0; j < 64; ++j) {
      s0 += b2[j] * w01[j*64 + c];
      s1 += b2[j] * w11[j*64 + c];
    }
    bias0[c] = s0;
    bias1[c] = s1;
  }
}

// 32 edges/block; fused weights staged in LDS; lane=channel -> coalesced writes
__global__ void __launch_bounds__(256) k_rad4(
    const float* __restrict__ bc,
    const float* __restrict__ w1, const float* __restrict__ b1,
    const float* __restrict__ M0, const float* __restrict__ M1,
    const float* __restrict__ bias0, const float* __restrict__ bias1,
    float* __restrict__ q0, bf16* __restrict__ q1b) {
  __shared__ float sM0[4096], sM1[4096], sW1[512];
  __shared__ float sB[64], sb0[64], sb1[64];
  __shared__ float sH[4][64], sBC[4][8];
  const int tid = threadIdx.x;
  const int j = tid >> 6, m = tid & 63;
  for (int i = tid; i < 4096; i += 256) { sM0[i] = M0[i]; sM1[i] = M1[i]; }
  for (int i = tid; i < 512; i += 256) sW1[i] = w1[i];
  if (tid < 64) { sB[tid] = b1[tid]; sb0[tid] = bias0[tid]; sb1[tid] = bias1[tid]; }
  __syncthreads();
  for (int g = 0; g < 8; ++g) {
    int e = blockIdx.x*32 + g*4 + j;
    int eL = e < E_EDGES ? e : E_EDGES-1;
    if (m < 8) sBC[j][m] = bc[(size_t)eL*8 + m];
    float t = sB[m];
    #pragma unroll
    for (int b = 0; b < 8; ++b) t += sBC[j][b]*sW1[b*64 + m];
    sH[j][m] = siluf(t);
    float a0 = sb0[m], a1 = sb1[m];
    for (int mm = 0; mm < 64; ++mm) {
      float hv = sH[j][mm];
      a0 += hv*sM0[mm*64 + m];
      a1 += hv*sM1[mm*64 + m];
    }
    if (e < E_EDGES) {
      q0[(size_t)e*64 + m] = siluf(a0);
      q1b[(size_t)e*64 + m] = __float2bfloat16(siluf(a1));
    }
  }
}

__global__ void k_embed(const float* __restrict__ emb, const int* __restrict__ an,
                        float* __restrict__ node0) {
  int i = blockIdx.x*256 + threadIdx.x;
  int n = i >> 6, c = i & 63;
  node0[i] = emb[an[n]*64 + c];
}

// reorder wnn0_w2[h, off_b + u*m3 + v] -> W0r[u*3584 + vp*64 + h]  (h-contiguous)
__global__ void k_w0r(const float* __restrict__ w, float* __restrict__ W0r) {
  int idx = blockIdx.x*256 + threadIdx.x;
  if (idx >= 64*3584) return;
  int u = idx / 3584, r = idx - u*3584;
  int vp = r >> 6, hh = r & 63;
  int boff, m3, v;
  if (vp < 32)      { boff = 0;    m3 = 32; v = vp; }
  else if (vp < 48) { boff = 2048; m3 = 16; v = vp - 32; }
  else              { boff = 3072; m3 = 8;  v = vp - 48; }
  W0r[idx] = w[hh*3584 + boff + u*m3 + v];
}

// transpose wnn1_w2 (64 x 3456) -> W2t[n][k] bf16 (original column order)
__global__ void k_w2t(const float* __restrict__ w, bf16* __restrict__ W2t) {
  int idx = blockIdx.x*256 + threadIdx.x;   // 221184
  int n = idx >> 6, k = idx & 63;
  W2t[idx] = __float2bfloat16(w[(size_t)k*3456 + n]);
}

// G0[n, vp*64+h] = sum_u node0[n,u] * W0r[u, vp*64+h]
__global__ void __launch_bounds__(256) k_g0(const float* __restrict__ node0,
    const float* __restrict__ W0r, bf16* __restrict__ G0) {
  __shared__ float ns[8][64];
  const int tid = threadIdx.x;
  const int col = blockIdx.x*256 + tid;
  const int nb = blockIdx.y*8;
  for (int i = tid; i < 512; i += 256)
    ns[i>>6][i&63] = node0[(size_t)(nb + (i>>6))*64 + (i&63)];
  __syncthreads();
  float acc[8] = {0,0,0,0,0,0,0,0};
  for (int u = 0; u < 64; ++u) {
    float wv = W0r[(size_t)u*3584 + col];
    #pragma unroll
    for (int n = 0; n < 8; ++n) acc[n] += ns[n][u]*wv;
  }
  #pragma unroll
  for (int n = 0; n < 8; ++n)
    G0[(size_t)(nb+n)*3584 + col] = __float2bfloat16(acc[n]);
}

// layer-0 message + aggregate: one wave per edge; vectorized G0 reads
__global__ void __launch_bounds__(256) k_msg0(
    const float* __restrict__ q0, const bf16* __restrict__ G0,
    const float* __restrict__ shb, const int* __restrict__ ei,
    float* __restrict__ agg0) {
  __shared__ float sq[4][64];
  const int tid = threadIdx.x;
  const int wave = tid >> 6;
  const int lane = tid & 63;
  const int e = blockIdx.x*4 + wave;
  for (int i = tid; i < 256; i += 256)
    sq[i>>6][i&63] = q0[(size_t)(blockIdx.x*4 + (i>>6))*64 + (i&63)];
  __syncthreads();
  const int src = ei[e], dst = ei[E_EDGES + e];
  float z = 0.f;
  if (lane < 56) {
    const short* gp = (const short*)G0 + (size_t)src*3584 + lane*64;
    #pragma unroll
    for (int hb = 0; hb < 8; ++hb) {
      short8 g = *(const short8*)(gp + hb*8);
      #pragma unroll
      for (int jj = 0; jj < 8; ++jj)
        z += sq[wave][hb*8+jj]*us2f((unsigned short)g[jj]);
    }
  }
  const float c = 0.125f * 0.3162277660168379f;
  float* ap = agg0 + (size_t)dst*120;
  const float* sh = shb + (size_t)e*12;
  if (lane < 32) {
    atomicAdd(ap + lane, z*c);
  } else if (lane < 48) {
    int v = lane - 32;
    #pragma unroll
    for (int k = 0; k < 3; ++k) atomicAdd(ap + 32 + v*3 + k, z*sh[1+k]*c);
  } else if (lane < 56) {
    int v = lane - 48;
    #pragma unroll
    for (int k = 0; k < 5; ++k) atomicAdd(ap + 80 + v*5 + k, z*sh[4+k]*c);
  }
}

__global__ void k_node1(const float* __restrict__ agg0, const float* __restrict__ node0,
                        const float* __restrict__ sc00, float* __restrict__ node1) {
  __shared__ float n0[64];
  int n = blockIdx.x, tid = threadIdx.x;
  if (tid < 64) n0[tid] = node0[(size_t)n*64 + tid];
  __syncthreads();
  if (tid >= 120) return;
  float v = agg0[(size_t)n*120 + tid];
  if (tid < 32) {
    float s = 0.f;
    for (int u = 0; u < 64; ++u) s += n0[u]*sc00[u*32 + tid];
    v += s * 0.125f;
    v = siluf(v);
  }
  node1[(size_t)n*120 + tid] = v;
}

// ---- layer-1 w-generation GEMM: w[e, n] = sum_k q1b[e,k] * W2t[n,k]  (MFMA bf16)
__global__ void __launch_bounds__(256) k_wgemm(
    const bf16* __restrict__ q1b, const bf16* __restrict__ W2t,
    bf16* __restrict__ wout, int e0, int nE) {
  __shared__ short lds[4][32*64];
  const int tid = threadIdx.x;
  const int wid = tid >> 6, lane = tid & 63;
  const int nt = blockIdx.x*4 + wid;
  const int r0 = blockIdx.y*32;
  const int row16 = lane & 15, quad = lane >> 4;

  short8 a[2][2];
  #pragma unroll
  for (int mi = 0; mi < 2; ++mi) {
    int r = r0 + mi*16 + row16;
    int rg = e0 + ((r < nE) ? r : 0);
    const short* ap = (const short*)q1b + (size_t)rg*64 + quad*8;
    a[mi][0] = *(const short8*)(ap);
    a[mi][1] = *(const short8*)(ap + 32);
  }
  if (nt < 54) {
    f32x4 acc[4][2] = {};
    #pragma unroll
    for (int ni = 0; ni < 4; ++ni) {
      int col = nt*64 + ni*16 + row16;
      const short* bp = (const short*)W2t + (size_t)col*64 + quad*8;
      short8 b0 = *(const short8*)(bp);
      short8 b1 = *(const short8*)(bp + 32);
      #pragma unroll
      for (int mi = 0; mi < 2; ++mi) {
        acc[ni][mi] = __builtin_amdgcn_mfma_f32_16x16x32_bf16(a[mi][0], b0, acc[ni][mi], 0,0,0);
        acc[ni][mi] = __builtin_amdgcn_mfma_f32_16x16x32_bf16(a[mi][1], b1, acc[ni][mi], 0,0,0);
      }
    }
    #pragma unroll
    for (int ni = 0; ni < 4; ++ni)
      #pragma unroll
      for (int mi = 0; mi < 2; ++mi)
        #pragma unroll
        for (int rr = 0; rr < 4; ++rr) {
          bf16 hv = __float2bfloat16(acc[ni][mi][rr]);
          lds[wid][(mi*16 + quad*4 + rr)*64 + ni*16 + row16] = *(short*)&hv;
        }
  }
  __syncthreads();
  if (nt < 54) {
    #pragma unroll
    for (int it = 0; it < 4; ++it) {
      int unit = it*64 + lane;
      int rrow = unit >> 3;
      int cu = (unit & 7) * 8;
      int r = r0 + rrow;
      if (r < nE)
        *(uint4*)((short*)wout + (size_t)r*3456 + nt*64 + cu) =
            *(const uint4*)&lds[wid][rrow*64 + cu];
    }
  }
}

// ---- layer-1 consume v3: ONE WAVE PER EDGE; no cross-wave comm, no shfl, no atomics in LDS
__global__ void __launch_bounds__(256) k_tp3(
    const bf16* __restrict__ wch, const float* __restrict__ node1,
    const float* __restrict__ shb, const int* __restrict__ ei,
    int e0, int nE, float* __restrict__ agg1) {
  __shared__ uint4 wl4[4][432];        // per-wave w row (3456 bf16)
  __shared__ float tl[4][592];
  __shared__ float ml[4][120];
  __shared__ float xl[4][120];
  __shared__ float shl[4][12];
  const int tid = threadIdx.x;
  const int wv = tid >> 6, lane = tid & 63;
  int elr = blockIdx.x*4 + wv;         // chunk-local edge
  const bool live = elr < nE;
  const int el = live ? elr : nE-1;
  const int eg = e0 + el;
  const int src = ei[eg], dst = ei[E_EDGES + eg];

  const uint4* wr = (const uint4*)(wch + (size_t)el*3456);
  for (int i = lane; i < 432; i += 64) wl4[wv][i] = wr[i];
  for (int i = lane; i < 120; i += 64) { xl[wv][i] = node1[(size_t)src*120 + i]; ml[wv][i] = 0.f; }
  if (lane < 12) shl[wv][lane] = shb[(size_t)eg*12 + lane];
  __syncthreads();

  // ---- build t (all scales literal; CG loops fully unrolled -> constant folding)
  {
    const float* x  = xl[wv];
    const float* sh = shl[wv];
    for (int idx = lane; idx < 592; idx += 64) {
      float t = 0.0f;
      if (idx < 32)       { t = x[idx] * 0.1336306209562122f; }
      else if (idx < 128) { int j = idx-32,  u=j/3, k=j-u*3; t = x[u]*sh[1+k] * 0.1178511301977579f; }
      else if (idx < 288) { int j = idx-128, u=j/5, k=j-u*5; t = x[u]*sh[4+k] * 0.125f; }
      else if (idx < 336) { int j = idx-288, u=j/3, k=j-u*3; t = x[32+u*3+k] * 0.1178511301977579f; }
      else if (idx < 352) { int u = idx-336;
        t = (x[32+u*3]*sh[1] + x[32+u*3+1]*sh[2] + x[32+u*3+2]*sh[3]) * 0.0771516749810460f; }
      else if (idx < 432) { int j = idx-352, u=j/5, k=j-u*5;
        const float A = 0.3162277660168379f, Bc = 0.1825741858350554f, B2 = 0.3651483716701107f;
        float s = 0.f;
        if (k == 0)      s = A*(x[32+u*3+0]*sh[3] + x[32+u*3+2]*sh[1]);
        else if (k == 1) s = A*(x[32+u*3+0]*sh[2] + x[32+u*3+1]*sh[1]);
        else if (k == 2) s = -Bc*x[32+u*3+0]*sh[1] + B2*x[32+u*3+1]*sh[2] - Bc*x[32+u*3+2]*sh[3];
        else if (k == 3) s = A*(x[32+u*3+1]*sh[3] + x[32+u*3+2]*sh[2]);
        else             s = -A*x[32+u*3+0]*sh[1] + A*x[32+u*3+2]*sh[3];
        t = s * 0.2795084971874737f; }
      else if (idx < 480) { int j = idx-432, u=j/3, k=j-u*3;
        const float A = 0.3162277660168379f, Bc = 0.1825741858350554f, B2 = 0.3651483716701107f;
        float s = 0.f;
        if (k == 0)      s = A*x[32+u*3+0]*sh[4+0] + A*x[32+u*3+1]*sh[4+1]
                           - Bc*x[32+u*3+0]*sh[4+2] - A*x[32+u*3+0]*sh[4+4];
        else if (k == 1) s = A*x[32+u*3+2]*sh[4+1] + B2*x[32+u*3+1]*sh[4+2]
                           + A*x[32+u*3+1]*sh[4+3] + A*x[32+u*3+0]*sh[4+0]*0.f
                           + A*x[32+u*3+2]*sh[4+0]*0.f;
        else             s = 0.f;
        // C121[i][j][k]=C112[i][k][j]: recompute explicitly below (branch above incomplete)
        s = 0.f;
        {
          // entries (i,kk,jj): from C112 (I,J,K): t += V * x[i] * sh[4+K] when J==k
          if (k == 0) { s += A *x[32+u*3+1]*sh[4+1];          // (1,0,1)
                        s += A *x[32+u*3+0]*sh[4+0];          // (0,0,... wait (0,0) no
          }
        }
        // fall through: use table loop (compile-time unrolled)
        {
          const int I_[11] = {0,2,0,1,1,2, 0,1,2, 0,2};
          const int J_[11] = {2,0,1,0,2,1, 0,1,2, 0,2};
          const int K_[11] = {0,0,1,1,3,3, 2,2,2, 4,4};
          const float V_[11] = {A,A,A,A,A,A, -Bc,B2,-Bc, -A,A};
          s = 0.f;
          #pragma unroll
          for (int q = 0; q < 11; ++q) if (J_[q] == k)
            s += V_[q]*x[32+u*3+I_[q]]*sh[4+K_[q]];
        }
        t = s * 0.2041241452319315f; }
      else if (idx < 520) { int j = idx-480, u=j/5, k=j-u*5; t = x[80+u*5+k] * 0.125f; }
      else if (idx < 544) { int j = idx-520, u=j/3, k=j-u*3;
        const float A = 0.3162277660168379f, Bc = 0.1825741858350554f, B2 = 0.3651483716701107f;
        const int I_[11] = {0,2,0,1,1,2, 0,1,2, 0,2};
        const int J_[11] = {2,0,1,0,2,1, 0,1,2, 0,2};
        const int K_[11] = {0,0,1,1,3,3, 2,2,2, 4,4};
        const float V_[11] = {A,A,A,A,A,A, -Bc,B2,-Bc, -A,A};
        float s = 0.f;
        #pragma unroll
        for (int q = 0; q < 11; ++q) if (J_[q] == k)
          s += V_[q]*x[80+u*5+K_[q]]*sh[1+I_[q]];
        t = s * 0.2041241452319315f; }
      else if (idx < 552) { int u = idx-544;
        float s = 0.f;
        #pragma unroll
        for (int q = 0; q < 5; ++q) s += x[80+u*5+q]*sh[4+q];
        t = s * 0.0597614304667197f; }
      else { int j = idx-552, u=j/5, k=j-u*5;
        const float P = 0.2390457218668787f, Q = 0.2070196678027063f, R = 0.1195228609334394f;
        const int I_[25] = {0,0,2, 0,0,1,1,3,3, 1,1,2, 1,1,4, 2, 2,3,3, 2,4,4, 3,3,4};
        const int J_[25] = {0,2,0, 1,3,0,3,0,1, 1,2,1, 1,4,1, 2, 3,2,3, 4,2,4, 3,4,3};
        const int K_[25] = {2,0,0, 3,1,3,0,1,0, 2,1,1, 4,1,1, 2, 3,3,2, 4,4,2, 4,3,3};
        const float V_[25] = {P,P,P, -Q,-Q,-Q,-Q,-Q,-Q, -R,-R,-R, Q,Q,Q, -P,
                              -R,-R,-R, P,P,P, -Q,-Q,-Q};
        float s = 0.f;
        #pragma unroll
        for (int q = 0; q < 25; ++q) if (K_[q] == k)
          s += V_[q]*x[80+u*5+I_[q]]*sh[4+J_[q]];
        t = s * 0.2795084971874737f; }
      tl[wv][idx] = t;
    }
  }
  __syncthreads();

  // ---- consume: lane = flat (v,k) output of each path; u-loop; no atomics
  {
    const short* w = (const short*)wl4[wv];
    const float* t = tl[wv];
    float* m = ml[wv];
    #define PATHC(OFF, M1C, M3C, NKC, MOFFC, TOFFC)                       \
      if (lane < (M3C)*(NKC)) {                                           \
        int v = lane / (NKC), k = lane - v*(NKC);                         \
        float a = 0.f;                                                    \
        _Pragma("unroll")                                                 \
        for (int u = 0; u < (M1C); ++u)                                   \
          a += us2f((unsigned short)w[(OFF)+u*(M3C)+v]) * t[(TOFFC)+u*(NKC)+k]; \
        m[(MOFFC)+lane] += a;                                             \
      }
    PATHC(0,    32, 32, 1, 0,   0)
    PATHC(1024, 32, 16, 3, 32,  32)
    PATHC(1536, 32, 8,  5, 80,  128)
    PATHC(1792, 16, 16, 3, 32,  288)
    PATHC(2048, 16, 32, 1, 0,   336)
    PATHC(2560, 16, 8,  5, 80,  352)
    PATHC(2688, 16, 16, 3, 32,  432)
    PATHC(2944, 8,  8,  5, 80,  480)
    PATHC(3008, 8,  16, 3, 32,  520)
    PATHC(3136, 8,  32, 1, 0,   544)
    PATHC(3392, 8,  8,  5, 80,  552)
    #undef PATHC
  }
  __syncthreads();

  if (live) {
    for (int i = lane; i < 120; i += 64)
      atomicAdd(&agg1[(size_t)dst*120 + i], ml[wv][i]*0.3162277660168379f);
  }
}

__global__ void k_out(const float* __restrict__ agg1, const float* __restrict__ node1,
                      const float* __restrict__ sc0e, const float* __restrict__ sc1o,
                      const float* __restrict__ sc2e, float* __restrict__ out) {
  __shared__ float x[120];
  int n = blockIdx.x, tid = threadIdx.x;
  if (tid < 120) x[tid] = node1[(size_t)n*120 + tid];
  __syncthreads();
  if (tid >= 120) return;
  float v = agg1[(size_t)n*120 + tid];
  if (tid < 32) {
    float s = 0.f;
    for (int u = 0; u < 32; ++u) s += x[u]*sc0e[u*32 + tid];
    v += s * 0.1767766952966369f;
  } else if (tid < 80) {
    int jj = tid - 32, vv = jj/3, k = jj - vv*3;
    float s = 0.f;
    for (int u = 0; u < 16; ++u) s += x[32 + u*3 + k]*sc1o[u*16 + vv];
    v += s * 0.25f;
  } else {
    int jj = tid - 80, vv = jj/5, k = jj - vv*5;
    float s = 0.f;
    for (int u = 0; u < 8; ++u) s += x[80 + u*5 + k]*sc2e[u*8 + vv];
    v += s * 0.3535533905932738f;
  }
  out[(size_t)n*120 + tid] = v;
}

// ---------------- launch ----------------
extern "C" void kernel_launch(void* const* d_in, const int* in_sizes, int n_in,
                              void* d_out, int out_size, void* d_ws, size_t ws_size,
                              hipStream_t stream) {
  const float* embed   = (const float*)d_in[1];
  const float* rad_w1  = (const float*)d_in[2];
  const float* rad_b1  = (const float*)d_in[3];
  const float* rad_w2  = (const float*)d_in[4];
  const float* rad_b2  = (const float*)d_in[5];
  const float* wnn0_w1 = (const float*)d_in[6];
  const float* wnn0_w2 = (const float*)d_in[7];
  const float* wnn1_w1 = (const float*)d_in[8];
  const float* wnn1_w2 = (const float*)d_in[9];
  const float* sc0_0e  = (const float*)d_in[10];
  const float* sc1_0e  = (const float*)d_in[11];
  const float* sc1_1o  = (const float*)d_in[12];
  const float* sc1_2e  = (const float*)d_in[13];
  const float* edge_vec = (const float*)d_in[14];
  const float* edge_len = (const float*)d_in[15];
  const int*  anum    = (const int*)d_in[16];
  const int*  ei      = (const int*)d_in[17];

  float* ws = (float*)d_ws;
  float* shbuf = ws;                      // 600000
  float* bc    = ws + 600000;             // 400000
  bf16*  q1b   = (bf16*)(ws + 1000000);   // 1.6M f-slots
  float* node0 = ws + 2600000;            // 320000
  float* W0r   = ws + 2920000;            // 229376
  bf16*  W2t   = (bf16*)(ws + 3149376);   // 110592 f-slots
  float* M0    = ws + 3259968;            // 4096
  float* M1    = ws + 3264064;            // 4096
  float* bias0 = ws + 3268160;            // 64
  float* bias1 = ws + 3268224;            // 64
  float* agg0  = ws + 3268288;            // 600000
  float* node1 = ws + 3868288;            // 600000
  float* agg1  = ws + 4468288;            // 600000
  float* q0    = ws + 5068288;            // 3200000
  bf16*  G0    = (bf16*)(ws + 8268288);   // -> end 17228288 (68.9 MB)
  bf16*  wchunk = (bf16*)(ws + 5068288);  // aliases q0+G0 (dead by layer-1)

  hipMemsetAsync(agg0, 0, 600000*sizeof(float), stream);
  hipMemsetAsync(agg1, 0, 600000*sizeof(float), stream);

  k_prep<<<(E_EDGES+255)/256, 256, 0, stream>>>(edge_vec, edge_len, shbuf, bc);
  k_fuse<<<16, 256, 0, stream>>>(rad_w2, rad_b2, wnn0_w1, wnn1_w1, M0, M1, bias0, bias1);
  k_rad4<<<(E_EDGES+31)/32, 256, 0, stream>>>(bc, rad_w1, rad_b1, M0, M1,
                                              bias0, bias1, q0, q1b);
  k_embed<<<(NN*64)/256, 256, 0, stream>>>(embed, anum, node0);
  k_w0r<<<(64*3584+255)/256, 256, 0, stream>>>(wnn0_w2, W0r);
  k_w2t<<<(64*3456)/256, 256, 0, stream>>>(wnn1_w2, W2t);
  k_g0<<<dim3(14, NN/8), 256, 0, stream>>>(node0, W0r, G0);
  k_msg0<<<E_EDGES/4, 256, 0, stream>>>(q0, G0, shbuf, ei, agg0);
  k_node1<<<NN, 128, 0, stream>>>(agg0, node0, sc0_0e, node1);

  for (int c = 0; c < 8; ++c) {
    int e0 = c * WCH;
    k_wgemm<<<dim3(14, (WCH+31)/32), 256, 0, stream>>>(q1b, W2t, wchunk, e0, WCH);
    k_tp3<<<(WCH+3)/4, 256, 0, stream>>>(wchunk, node1, shbuf, ei, e0, WCH, agg1);
  }
  k_out<<<NN, 128, 0, stream>>>(agg1, node1, sc1_0e, sc1_1o, sc1_2e, (float*)d_out);
}

// Round 8
// 681.428 us; speedup vs baseline: 1.8306x; 1.2056x over previous
//
#include <hip/hip_runtime.h>
#include <hip/hip_bf16.h>
#include <math.h>

#define E_EDGES 50000
#define NN 5000

typedef __hip_bfloat16 bf16;
typedef __attribute__((ext_vector_type(8))) short short8;
typedef __attribute__((ext_vector_type(4))) float f32x4;

__device__ __forceinline__ float b2f(bf16 v) { return __bfloat162float(v); }
__device__ __forceinline__ float siluf(float x) { return x / (1.0f + __expf(-x)); }
__device__ __forceinline__ float us2f(unsigned short u) {
  union { unsigned int i; float f; } c; c.i = ((unsigned int)u) << 16; return c.f;
}

// ================= merged setup: prep | fuse | embed | w0r | w2t =================
__global__ void __launch_bounds__(256) k_setup(
    const float* __restrict__ evec, const float* __restrict__ elen,
    float* __restrict__ shb, float* __restrict__ bc,
    const float* __restrict__ w2, const float* __restrict__ b2,
    const float* __restrict__ w01, const float* __restrict__ w11,
    float* __restrict__ M0, float* __restrict__ M1,
    float* __restrict__ bias0, float* __restrict__ bias1,
    const float* __restrict__ emb, const int* __restrict__ an,
    float* __restrict__ node0,
    const float* __restrict__ w0, float* __restrict__ W0r,
    const float* __restrict__ w1w2, bf16* __restrict__ W2t) {
  const int b = blockIdx.x, tid = threadIdx.x;
  if (b < 196) {                      // ---- prep (sh + basis*cutoff)
    int e = b*256 + tid;
    if (e >= E_EDGES) return;
    float x = evec[3*e+0], y = evec[3*e+1], z = evec[3*e+2];
    float r = elen[e];
    float inv = 1.0f / (r + 1e-8f);
    float ux = x*inv, uy = y*inv, uz = z*inv;
    const float s3 = 1.7320508075688772f, s5 = 2.2360679774997896f, s15 = 3.8729833462074170f;
    float* sh = shb + (size_t)e*12;
    sh[0] = 1.0f;
    sh[1] = s3*uy; sh[2] = s3*uz; sh[3] = s3*ux;
    sh[4] = s15*ux*uy; sh[5] = s15*uy*uz; sh[6] = 0.5f*s5*(3.0f*uz*uz - 1.0f);
    sh[7] = s15*ux*uz; sh[8] = 0.5f*s15*(ux*ux - uy*uy);
    sh[9] = 0.f; sh[10] = 0.f; sh[11] = 0.f;
    float rr = fmaxf(r, 1e-8f);
    const float pi = 3.14159265358979f;
    float xr = r * 0.2f;
    float cut = (xr < 1.0f) ? 0.5f*(1.0f + cosf(pi*xr)) : 0.0f;
    float fb = pi * 0.2f;
    for (int k = 1; k <= 8; ++k)
      bc[(size_t)e*8 + (k-1)] = sinf(fb*(float)k*r)/rr * cut;
  } else if (b < 212) {               // ---- fuse rad_w2 into wnn*_w1
    int i = (b-196)*256 + tid;        // 4096
    int hh = i >> 6, c = i & 63;
    float a0 = 0.f, a1 = 0.f;
    for (int j = 0; j < 64; ++j) {
      float wv = w2[hh*64 + j];
      a0 += wv * w01[j*64 + c];
      a1 += wv * w11[j*64 + c];
    }
    M0[hh*64 + c] = a0;
    M1[hh*64 + c] = a1;
    if (hh == 0) {
      float s0 = 0.f, s1 = 0.f;
      for (int j = 0; j < 64; ++j) {
        s0 += b2[j] * w01[j*64 + c];
        s1 += b2[j] * w11[j*64 + c];
      }
      bias0[c] = s0;
      bias1[c] = s1;
    }
  } else if (b < 1462) {              // ---- embed (320000 exact)
    int i = (b-212)*256 + tid;
    int n = i >> 6, c = i & 63;
    node0[i] = emb[an[n]*64 + c];
  } else if (b < 2358) {              // ---- w0r reorder (229376 exact)
    int idx = (b-1462)*256 + tid;
    int u = idx / 3584, r = idx - u*3584;
    int vp = r >> 6, hh = r & 63;
    int boff, m3, v;
    if (vp < 32)      { boff = 0;    m3 = 32; v = vp; }
    else if (vp < 48) { boff = 2048; m3 = 16; v = vp - 32; }
    else              { boff = 3072; m3 = 8;  v = vp - 48; }
    W0r[idx] = w0[hh*3584 + boff + u*m3 + v];
  } else {                            // ---- w2t transpose (221184 exact)
    int idx = (b-2358)*256 + tid;
    int n = idx >> 6, k = idx & 63;
    W2t[idx] = __float2bfloat16(w1w2[(size_t)k*3456 + n]);
  }
}

// ================= merged mid: rad4 | g0 =================
__global__ void __launch_bounds__(256) k_mid(
    const float* __restrict__ bc,
    const float* __restrict__ w1, const float* __restrict__ b1,
    const float* __restrict__ M0, const float* __restrict__ M1,
    const float* __restrict__ bias0, const float* __restrict__ bias1,
    float* __restrict__ q0, bf16* __restrict__ q1b,
    const float* __restrict__ node0, const float* __restrict__ W0r,
    bf16* __restrict__ G0) {
  __shared__ float smem[9184];
  const int tid = threadIdx.x;
  const int b = blockIdx.x;
  if (b < 1563) {
    // ---- rad4: 32 edges/block
    float* sM0 = smem;          float* sM1 = smem + 4096;
    float* sW1 = smem + 8192;   float* sB  = smem + 8704;
    float* sb0 = smem + 8768;   float* sb1 = smem + 8832;
    float* sH  = smem + 8896;   float* sBC = smem + 9152;   // [4][64], [4][8]
    const int j = tid >> 6, m = tid & 63;
    for (int i = tid; i < 4096; i += 256) { sM0[i] = M0[i]; sM1[i] = M1[i]; }
    for (int i = tid; i < 512; i += 256) sW1[i] = w1[i];
    if (tid < 64) { sB[tid] = b1[tid]; sb0[tid] = bias0[tid]; sb1[tid] = bias1[tid]; }
    __syncthreads();
    for (int g = 0; g < 8; ++g) {
      int e = b*32 + g*4 + j;
      int eL = e < E_EDGES ? e : E_EDGES-1;
      if (m < 8) sBC[j*8+m] = bc[(size_t)eL*8 + m];
      float t = sB[m];
      #pragma unroll
      for (int bb = 0; bb < 8; ++bb) t += sBC[j*8+bb]*sW1[bb*64 + m];
      sH[j*64+m] = siluf(t);
      float a0 = sb0[m], a1 = sb1[m];
      for (int mm = 0; mm < 64; ++mm) {
        float hv = sH[j*64+mm];
        a0 += hv*sM0[mm*64 + m];
        a1 += hv*sM1[mm*64 + m];
      }
      if (e < E_EDGES) {
        q0[(size_t)e*64 + m] = siluf(a0);
        q1b[(size_t)e*64 + m] = __float2bfloat16(siluf(a1));
      }
    }
  } else {
    // ---- g0: G0[n, vp*64+h] = sum_u node0[n,u]*W0r[u, vp*64+h]
    int bb = b - 1563;
    const int col = (bb % 14)*256 + tid;
    const int nb = (bb / 14)*8;
    float* ns = smem;   // [8][64]
    for (int i = tid; i < 512; i += 256)
      ns[i] = node0[(size_t)(nb + (i>>6))*64 + (i&63)];
    __syncthreads();
    float acc[8] = {0,0,0,0,0,0,0,0};
    for (int u = 0; u < 64; ++u) {
      float wv = W0r[(size_t)u*3584 + col];
      #pragma unroll
      for (int n = 0; n < 8; ++n) acc[n] += ns[n*64+u]*wv;
    }
    #pragma unroll
    for (int n = 0; n < 8; ++n)
      G0[(size_t)(nb+n)*3584 + col] = __float2bfloat16(acc[n]);
  }
}

// ================= layer-0 message: 2 edges per wave (2x MLP) =================
__global__ void __launch_bounds__(256) k_msg0b(
    const float* __restrict__ q0, const bf16* __restrict__ G0,
    const float* __restrict__ shb, const int* __restrict__ ei,
    float* __restrict__ agg0) {
  __shared__ float sq[8][64];
  const int tid = threadIdx.x;
  const int wave = tid >> 6;
  const int lane = tid & 63;
  const int ebase = blockIdx.x*8;
  for (int i = tid; i < 512; i += 256)
    sq[i>>6][i&63] = q0[(size_t)(ebase + (i>>6))*64 + (i&63)];
  __syncthreads();
  const int e0 = ebase + wave*2, e1 = e0 + 1;
  const int src0 = ei[e0], src1 = ei[e1];
  const int dst0 = ei[E_EDGES + e0], dst1 = ei[E_EDGES + e1];
  float z0 = 0.f, z1 = 0.f;
  if (lane < 56) {
    const short* gp0 = (const short*)G0 + (size_t)src0*3584 + lane*64;
    const short* gp1 = (const short*)G0 + (size_t)src1*3584 + lane*64;
    short8 ga[8], gb[8];
    #pragma unroll
    for (int hb = 0; hb < 8; ++hb) { ga[hb] = *(const short8*)(gp0 + hb*8);
                                     gb[hb] = *(const short8*)(gp1 + hb*8); }
    #pragma unroll
    for (int hb = 0; hb < 8; ++hb) {
      #pragma unroll
      for (int jj = 0; jj < 8; ++jj) {
        float qa = sq[wave*2  ][hb*8+jj];
        float qb = sq[wave*2+1][hb*8+jj];
        z0 += qa*us2f((unsigned short)ga[hb][jj]);
        z1 += qb*us2f((unsigned short)gb[hb][jj]);
      }
    }
  }
  const float c = 0.125f * 0.3162277660168379f;
  #pragma unroll
  for (int pass = 0; pass < 2; ++pass) {
    float z = pass ? z1 : z0;
    int e = pass ? e1 : e0;
    float* ap = agg0 + (size_t)(pass ? dst1 : dst0)*120;
    const float* sh = shb + (size_t)e*12;
    if (lane < 32) {
      atomicAdd(ap + lane, z*c);
    } else if (lane < 48) {
      int v = lane - 32;
      #pragma unroll
      for (int k = 0; k < 3; ++k) atomicAdd(ap + 32 + v*3 + k, z*sh[1+k]*c);
    } else if (lane < 56) {
      int v = lane - 48;
      #pragma unroll
      for (int k = 0; k < 5; ++k) atomicAdd(ap + 80 + v*5 + k, z*sh[4+k]*c);
    }
  }
}

__global__ void k_node1(const float* __restrict__ agg0, const float* __restrict__ node0,
                        const float* __restrict__ sc00, float* __restrict__ node1) {
  __shared__ float n0[64];
  int n = blockIdx.x, tid = threadIdx.x;
  if (tid < 64) n0[tid] = node0[(size_t)n*64 + tid];
  __syncthreads();
  if (tid >= 120) return;
  float v = agg0[(size_t)n*120 + tid];
  if (tid < 32) {
    float s = 0.f;
    for (int u = 0; u < 64; ++u) s += n0[u]*sc00[u*32 + tid];
    v += s * 0.125f;
    v = siluf(v);
  }
  node1[(size_t)n*120 + tid] = v;
}

// ================= layer-1 w GEMM (MFMA bf16) =================
__global__ void __launch_bounds__(256) k_wgemm(
    const bf16* __restrict__ q1b, const bf16* __restrict__ W2t,
    bf16* __restrict__ wout, int e0, int nE) {
  __shared__ short lds[4][32*64];
  const int tid = threadIdx.x;
  const int wid = tid >> 6, lane = tid & 63;
  const int nt = blockIdx.x*4 + wid;
  const int r0 = blockIdx.y*32;
  const int row16 = lane & 15, quad = lane >> 4;

  short8 a[2][2];
  #pragma unroll
  for (int mi = 0; mi < 2; ++mi) {
    int r = r0 + mi*16 + row16;
    int rg = e0 + ((r < nE) ? r : 0);
    const short* ap = (const short*)q1b + (size_t)rg*64 + quad*8;
    a[mi][0] = *(const short8*)(ap);
    a[mi][1] = *(const short8*)(ap + 32);
  }
  if (nt < 54) {
    f32x4 acc[4][2] = {};
    #pragma unroll
    for (int ni = 0; ni < 4; ++ni) {
      int col = nt*64 + ni*16 + row16;
      const short* bp = (const short*)W2t + (size_t)col*64 + quad*8;
      short8 b0 = *(const short8*)(bp);
      short8 b1 = *(const short8*)(bp + 32);
      #pragma unroll
      for (int mi = 0; mi < 2; ++mi) {
        acc[ni][mi] = __builtin_amdgcn_mfma_f32_16x16x32_bf16(a[mi][0], b0, acc[ni][mi], 0,0,0);
        acc[ni][mi] = __builtin_amdgcn_mfma_f32_16x16x32_bf16(a[mi][1], b1, acc[ni][mi], 0,0,0);
      }
    }
    #pragma unroll
    for (int ni = 0; ni < 4; ++ni)
      #pragma unroll
      for (int mi = 0; mi < 2; ++mi)
        #pragma unroll
        for (int rr = 0; rr < 4; ++rr) {
          bf16 hv = __float2bfloat16(acc[ni][mi][rr]);
          lds[wid][(mi*16 + quad*4 + rr)*64 + ni*16 + row16] = *(short*)&hv;
        }
  }
  __syncthreads();
  if (nt < 54) {
    #pragma unroll
    for (int it = 0; it < 4; ++it) {
      int unit = it*64 + lane;
      int rrow = unit >> 3;
      int cu = (unit & 7) * 8;
      int r = r0 + rrow;
      if (r < nE)
        *(uint4*)((short*)wout + (size_t)r*3456 + nt*64 + cu) =
            *(const uint4*)&lds[wid][rrow*64 + cu];
    }
  }
}

// ================= layer-1 consume: one wave per edge =================
__global__ void __launch_bounds__(256) k_tp3(
    const bf16* __restrict__ wch, const float* __restrict__ node1,
    const float* __restrict__ shb, const int* __restrict__ ei,
    int e0, int nE, float* __restrict__ agg1) {
  __shared__ uint4 wl4[4][432];
  __shared__ float tl[4][592];
  __shared__ float ml[4][120];
  __shared__ float xl[4][120];
  __shared__ float shl[4][12];
  const int tid = threadIdx.x;
  const int wv = tid >> 6, lane = tid & 63;
  int elr = blockIdx.x*4 + wv;
  const bool live = elr < nE;
  const int el = live ? elr : nE-1;
  const int eg = e0 + el;
  const int src = ei[eg], dst = ei[E_EDGES + eg];

  const uint4* wr = (const uint4*)(wch + (size_t)el*3456);
  for (int i = lane; i < 432; i += 64) wl4[wv][i] = wr[i];
  for (int i = lane; i < 120; i += 64) { xl[wv][i] = node1[(size_t)src*120 + i]; ml[wv][i] = 0.f; }
  if (lane < 12) shl[wv][lane] = shb[(size_t)eg*12 + lane];
  __syncthreads();

  {
    const float* x  = xl[wv];
    const float* sh = shl[wv];
    const float A = 0.3162277660168379f, Bc = 0.1825741858350554f, B2 = 0.3651483716701107f;
    const int I_[11] = {0,2,0,1,1,2, 0,1,2, 0,2};
    const int J_[11] = {2,0,1,0,2,1, 0,1,2, 0,2};
    const int K_[11] = {0,0,1,1,3,3, 2,2,2, 4,4};
    const float V_[11] = {A,A,A,A,A,A, -Bc,B2,-Bc, -A,A};
    for (int idx = lane; idx < 592; idx += 64) {
      float t = 0.0f;
      if (idx < 32)       { t = x[idx] * 0.1336306209562122f; }
      else if (idx < 128) { int j = idx-32,  u=j/3, k=j-u*3; t = x[u]*sh[1+k] * 0.1178511301977579f; }
      else if (idx < 288) { int j = idx-128, u=j/5, k=j-u*5; t = x[u]*sh[4+k] * 0.125f; }
      else if (idx < 336) { int j = idx-288, u=j/3, k=j-u*3; t = x[32+u*3+k] * 0.1178511301977579f; }
      else if (idx < 352) { int u = idx-336;
        t = (x[32+u*3]*sh[1] + x[32+u*3+1]*sh[2] + x[32+u*3+2]*sh[3]) * 0.0771516749810460f; }
      else if (idx < 432) { int j = idx-352, u=j/5, k=j-u*5;
        float s = 0.f;
        #pragma unroll
        for (int q = 0; q < 11; ++q) if (K_[q] == k)
          s += V_[q]*x[32+u*3+I_[q]]*sh[1+J_[q]];
        t = s * 0.2795084971874737f; }
      else if (idx < 480) { int j = idx-432, u=j/3, k=j-u*3;
        float s = 0.f;
        #pragma unroll
        for (int q = 0; q < 11; ++q) if (J_[q] == k)
          s += V_[q]*x[32+u*3+I_[q]]*sh[4+K_[q]];
        t = s * 0.2041241452319315f; }
      else if (idx < 520) { int j = idx-480, u=j/5, k=j-u*5; t = x[80+u*5+k] * 0.125f; }
      else if (idx < 544) { int j = idx-520, u=j/3, k=j-u*3;
        float s = 0.f;
        #pragma unroll
        for (int q = 0; q < 11; ++q) if (J_[q] == k)
          s += V_[q]*x[80+u*5+K_[q]]*sh[1+I_[q]];
        t = s * 0.2041241452319315f; }
      else if (idx < 552) { int u = idx-544;
        float s = 0.f;
        #pragma unroll
        for (int q = 0; q < 5; ++q) s += x[80+u*5+q]*sh[4+q];
        t = s * 0.0597614304667197f; }
      else { int j = idx-552, u=j/5, k=j-u*5;
        const float P = 0.2390457218668787f, Q = 0.2070196678027063f, R = 0.1195228609334394f;
        const int I2_[25] = {0,0,2, 0,0,1,1,3,3, 1,1,2, 1,1,4, 2, 2,3,3, 2,4,4, 3,3,4};
        const int J2_[25] = {0,2,0, 1,3,0,3,0,1, 1,2,1, 1,4,1, 2, 3,2,3, 4,2,4, 3,4,3};
        const int K2_[25] = {2,0,0, 3,1,3,0,1,0, 2,1,1, 4,1,1, 2, 3,3,2, 4,4,2, 4,3,3};
        const float V2_[25] = {P,P,P, -Q,-Q,-Q,-Q,-Q,-Q, -R,-R,-R, Q,Q,Q, -P,
                               -R,-R,-R, P,P,P, -Q,-Q,-Q};
        float s = 0.f;
        #pragma unroll
        for (int q = 0; q < 25; ++q) if (K2_[q] == k)
          s += V2_[q]*x[80+u*5+I2_[q]]*sh[4+J2_[q]];
        t = s * 0.2795084971874737f; }
      tl[wv][idx] = t;
    }
  }
  __syncthreads();

  {
    const short* w = (const short*)wl4[wv];
    const float* t = tl[wv];
    float* m = ml[wv];
    #define PATHC(OFF, M1C, M3C, NKC, MOFFC, TOFFC)                       \
      if (lane < (M3C)*(NKC)) {                                           \
        int v = lane / (NKC), k = lane - v*(NKC);                         \
        float a = 0.f;                                                    \
        _Pragma("unroll")                                                 \
        for (int u = 0; u < (M1C); ++u)                                   \
          a += us2f((unsigned short)w[(OFF)+u*(M3C)+v]) * t[(TOFFC)+u*(NKC)+k]; \
        m[(MOFFC)+lane] += a;                                             \
      }
    PATHC(0,    32, 32, 1, 0,   0)
    PATHC(1024, 32, 16, 3, 32,  32)
    PATHC(1536, 32, 8,  5, 80,  128)
    PATHC(1792, 16, 16, 3, 32,  288)
    PATHC(2048, 16, 32, 1, 0,   336)
    PATHC(2560, 16, 8,  5, 80,  352)
    PATHC(2688, 16, 16, 3, 32,  432)
    PATHC(2944, 8,  8,  5, 80,  480)
    PATHC(3008, 8,  16, 3, 32,  520)
    PATHC(3136, 8,  32, 1, 0,   544)
    PATHC(3392, 8,  8,  5, 80,  552)
    #undef PATHC
  }
  __syncthreads();

  if (live) {
    for (int i = lane; i < 120; i += 64)
      atomicAdd(&agg1[(size_t)dst*120 + i], ml[wv][i]*0.3162277660168379f);
  }
}

__global__ void k_out(const float* __restrict__ agg1, const float* __restrict__ node1,
                      const float* __restrict__ sc0e, const float* __restrict__ sc1o,
                      const float* __restrict__ sc2e, float* __restrict__ out) {
  __shared__ float x[120];
  int n = blockIdx.x, tid = threadIdx.x;
  if (tid < 120) x[tid] = node1[(size_t)n*120 + tid];
  __syncthreads();
  if (tid >= 120) return;
  float v = agg1[(size_t)n*120 + tid];
  if (tid < 32) {
    float s = 0.f;
    for (int u = 0; u < 32; ++u) s += x[u]*sc0e[u*32 + tid];
    v += s * 0.1767766952966369f;
  } else if (tid < 80) {
    int jj = tid - 32, vv = jj/3, k = jj - vv*3;
    float s = 0.f;
    for (int u = 0; u < 16; ++u) s += x[32 + u*3 + k]*sc1o[u*16 + vv];
    v += s * 0.25f;
  } else {
    int jj = tid - 80, vv = jj/5, k = jj - vv*5;
    float s = 0.f;
    for (int u = 0; u < 8; ++u) s += x[80 + u*5 + k]*sc2e[u*8 + vv];
    v += s * 0.3535533905932738f;
  }
  out[(size_t)n*120 + tid] = v;
}

// ---------------- launch ----------------
extern "C" void kernel_launch(void* const* d_in, const int* in_sizes, int n_in,
                              void* d_out, int out_size, void* d_ws, size_t ws_size,
                              hipStream_t stream) {
  const float* embed   = (const float*)d_in[1];
  const float* rad_w1  = (const float*)d_in[2];
  const float* rad_b1  = (const float*)d_in[3];
  const float* rad_w2  = (const float*)d_in[4];
  const float* rad_b2  = (const float*)d_in[5];
  const float* wnn0_w1 = (const float*)d_in[6];
  const float* wnn0_w2 = (const float*)d_in[7];
  const float* wnn1_w1 = (const float*)d_in[8];
  const float* wnn1_w2 = (const float*)d_in[9];
  const float* sc0_0e  = (const float*)d_in[10];
  const float* sc1_0e  = (const float*)d_in[11];
  const float* sc1_1o  = (const float*)d_in[12];
  const float* sc1_2e  = (const float*)d_in[13];
  const float* edge_vec = (const float*)d_in[14];
  const float* edge_len = (const float*)d_in[15];
  const int*  anum    = (const int*)d_in[16];
  const int*  ei      = (const int*)d_in[17];

  float* ws = (float*)d_ws;
  float* shbuf = ws;                      // 600000
  float* bc    = ws + 600000;             // 400000
  bf16*  q1b   = (bf16*)(ws + 1000000);   // 1.6M f-slots
  float* node0 = ws + 2600000;            // 320000
  float* W0r   = ws + 2920000;            // 229376
  bf16*  W2t   = (bf16*)(ws + 3149376);   // 110592 f-slots
  float* M0    = ws + 3259968;            // 4096
  float* M1    = ws + 3264064;            // 4096
  float* bias0 = ws + 3268160;            // 64
  float* bias1 = ws + 3268224;            // 64
  float* agg0  = ws + 3268288;            // 600000
  float* agg1  = ws + 3868288;            // 600000 (adjacent -> one memset)
  float* node1 = ws + 4468288;            // 600000
  float* q0    = ws + 5068288;            // 3200000
  bf16*  G0    = (bf16*)(ws + 8268288);   // 8.96M f-slots -> base end 17228288 (68.9 MB)

  // layer-1 w buffer: pick the largest chunk that fits in ws
  long long CH; bf16* wbuf;
  const size_t base_end = 17228288ull;
  if      (ws_size >= (base_end + 86400000ull)*4) { CH = 50000; wbuf = (bf16*)(ws + base_end); }
  else if (ws_size >= (base_end + 43200000ull)*4) { CH = 25000; wbuf = (bf16*)(ws + base_end); }
  else if (ws_size >= (base_end + 21600000ull)*4) { CH = 12500; wbuf = (bf16*)(ws + base_end); }
  else                                            { CH = 6250;  wbuf = (bf16*)(ws + 5068288); } // alias q0+G0

  hipMemsetAsync(agg0, 0, 1200000*sizeof(float), stream);   // agg0 + agg1

  k_setup<<<3222, 256, 0, stream>>>(edge_vec, edge_len, shbuf, bc,
                                    rad_w2, rad_b2, wnn0_w1, wnn1_w1, M0, M1, bias0, bias1,
                                    embed, anum, node0,
                                    wnn0_w2, W0r, wnn1_w2, W2t);
  k_mid<<<1563 + 8750, 256, 0, stream>>>(bc, rad_w1, rad_b1, M0, M1, bias0, bias1,
                                         q0, q1b, node0, W0r, G0);
  k_msg0b<<<E_EDGES/8, 256, 0, stream>>>(q0, G0, shbuf, ei, agg0);
  k_node1<<<NN, 128, 0, stream>>>(agg0, node0, sc0_0e, node1);

  for (long long e0 = 0; e0 < E_EDGES; e0 += CH) {
    k_wgemm<<<dim3(14, (unsigned)((CH+31)/32), 1), 256, 0, stream>>>(q1b, W2t, wbuf, (int)e0, (int)CH);
    k_tp3<<<(unsigned)((CH+3)/4), 256, 0, stream>>>(wbuf, node1, shbuf, ei, (int)e0, (int)CH, agg1);
  }
  k_out<<<NN, 128, 0, stream>>>(agg1, node1, sc1_0e, sc1_1o, sc1_2e, (float*)d_out);
}

// Round 9
// 600.825 us; speedup vs baseline: 2.0761x; 1.1342x over previous
//
#include <hip/hip_runtime.h>
#include <hip/hip_bf16.h>
#include <math.h>

#define E_EDGES 50000
#define NN 5000

typedef __hip_bfloat16 bf16;
typedef __attribute__((ext_vector_type(8))) short short8;
typedef __attribute__((ext_vector_type(4))) float f32x4;

__device__ __forceinline__ float b2f(bf16 v) { return __bfloat162float(v); }
__device__ __forceinline__ float siluf(float x) { return x / (1.0f + __expf(-x)); }
__device__ __forceinline__ float us2f(unsigned short u) {
  union { unsigned int i; float f; } c; c.i = ((unsigned int)u) << 16; return c.f;
}

// ================= merged setup: prep | fuse | embed | w0r | w2t(permuted) =================
__global__ void __launch_bounds__(256) k_setup(
    const float* __restrict__ evec, const float* __restrict__ elen,
    float* __restrict__ shb, float* __restrict__ bc,
    const float* __restrict__ w2, const float* __restrict__ b2,
    const float* __restrict__ w01, const float* __restrict__ w11,
    float* __restrict__ M0, float* __restrict__ M1,
    float* __restrict__ bias0, float* __restrict__ bias1,
    const float* __restrict__ emb, const int* __restrict__ an,
    float* __restrict__ node0,
    const float* __restrict__ w0, float* __restrict__ W0r,
    const float* __restrict__ w1w2, bf16* __restrict__ W2t) {
  const int b = blockIdx.x, tid = threadIdx.x;
  if (b < 196) {                      // ---- prep (sh + basis*cutoff)
    int e = b*256 + tid;
    if (e >= E_EDGES) return;
    float x = evec[3*e+0], y = evec[3*e+1], z = evec[3*e+2];
    float r = elen[e];
    float inv = 1.0f / (r + 1e-8f);
    float ux = x*inv, uy = y*inv, uz = z*inv;
    const float s3 = 1.7320508075688772f, s5 = 2.2360679774997896f, s15 = 3.8729833462074170f;
    float* sh = shb + (size_t)e*12;
    sh[0] = 1.0f;
    sh[1] = s3*uy; sh[2] = s3*uz; sh[3] = s3*ux;
    sh[4] = s15*ux*uy; sh[5] = s15*uy*uz; sh[6] = 0.5f*s5*(3.0f*uz*uz - 1.0f);
    sh[7] = s15*ux*uz; sh[8] = 0.5f*s15*(ux*ux - uy*uy);
    sh[9] = 0.f; sh[10] = 0.f; sh[11] = 0.f;
    float rr = fmaxf(r, 1e-8f);
    const float pi = 3.14159265358979f;
    float xr = r * 0.2f;
    float cut = (xr < 1.0f) ? 0.5f*(1.0f + cosf(pi*xr)) : 0.0f;
    float fb = pi * 0.2f;
    for (int k = 1; k <= 8; ++k)
      bc[(size_t)e*8 + (k-1)] = sinf(fb*(float)k*r)/rr * cut;
  } else if (b < 212) {               // ---- fuse rad_w2 into wnn*_w1
    int i = (b-196)*256 + tid;        // 4096
    int hh = i >> 6, c = i & 63;
    float a0 = 0.f, a1 = 0.f;
    for (int j = 0; j < 64; ++j) {
      float wv = w2[hh*64 + j];
      a0 += wv * w01[j*64 + c];
      a1 += wv * w11[j*64 + c];
    }
    M0[hh*64 + c] = a0;
    M1[hh*64 + c] = a1;
    if (hh == 0) {
      float s0 = 0.f, s1 = 0.f;
      for (int j = 0; j < 64; ++j) {
        s0 += b2[j] * w01[j*64 + c];
        s1 += b2[j] * w11[j*64 + c];
      }
      bias0[c] = s0;
      bias1[c] = s1;
    }
  } else if (b < 1462) {              // ---- embed (320000 exact)
    int i = (b-212)*256 + tid;
    int n = i >> 6, c = i & 63;
    node0[i] = emb[an[n]*64 + c];
  } else if (b < 2358) {              // ---- w0r reorder (229376 exact)
    int idx = (b-1462)*256 + tid;
    int u = idx / 3584, r = idx - u*3584;
    int vp = r >> 6, hh = r & 63;
    int boff, m3, v;
    if (vp < 32)      { boff = 0;    m3 = 32; v = vp; }
    else if (vp < 48) { boff = 2048; m3 = 16; v = vp - 32; }
    else              { boff = 3072; m3 = 8;  v = vp - 48; }
    W0r[idx] = w0[hh*3584 + boff + u*m3 + v];
  } else {                            // ---- w2t transpose + per-path [v][u] permute
    int idx = (b-2358)*256 + tid;     // 221184 exact
    int nn = idx >> 6, k = idx & 63;
    int p, loc;
    if (nn < 1024)      { p=0;  loc=nn;      }
    else if (nn < 1536) { p=1;  loc=nn-1024; }
    else if (nn < 1792) { p=2;  loc=nn-1536; }
    else if (nn < 2048) { p=3;  loc=nn-1792; }
    else if (nn < 2560) { p=4;  loc=nn-2048; }
    else if (nn < 2688) { p=5;  loc=nn-2560; }
    else if (nn < 2944) { p=6;  loc=nn-2688; }
    else if (nn < 3008) { p=7;  loc=nn-2944; }
    else if (nn < 3136) { p=8;  loc=nn-3008; }
    else if (nn < 3392) { p=9;  loc=nn-3136; }
    else                { p=10; loc=nn-3392; }
    const int M1s[11] = {32,32,32,16,16,16,16,8,8,8,8};
    const int M3s[11] = {32,16,8,16,32,8,16,8,16,32,8};
    int m1 = M1s[p], m3 = M3s[p];
    int v = loc / m1, u = loc - v*m1;
    int src = (nn - loc) + u*m3 + v;
    W2t[idx] = __float2bfloat16(w1w2[(size_t)k*3456 + src]);
  }
}

// ================= merged mid: rad4 | g0 =================
__global__ void __launch_bounds__(256) k_mid(
    const float* __restrict__ bc,
    const float* __restrict__ w1, const float* __restrict__ b1,
    const float* __restrict__ M0, const float* __restrict__ M1,
    const float* __restrict__ bias0, const float* __restrict__ bias1,
    float* __restrict__ q0, bf16* __restrict__ q1b,
    const float* __restrict__ node0, const float* __restrict__ W0r,
    bf16* __restrict__ G0) {
  __shared__ float smem[9184];
  const int tid = threadIdx.x;
  const int b = blockIdx.x;
  if (b < 1563) {
    float* sM0 = smem;          float* sM1 = smem + 4096;
    float* sW1 = smem + 8192;   float* sB  = smem + 8704;
    float* sb0 = smem + 8768;   float* sb1 = smem + 8832;
    float* sH  = smem + 8896;   float* sBC = smem + 9152;
    const int j = tid >> 6, m = tid & 63;
    for (int i = tid; i < 4096; i += 256) { sM0[i] = M0[i]; sM1[i] = M1[i]; }
    for (int i = tid; i < 512; i += 256) sW1[i] = w1[i];
    if (tid < 64) { sB[tid] = b1[tid]; sb0[tid] = bias0[tid]; sb1[tid] = bias1[tid]; }
    __syncthreads();
    for (int g = 0; g < 8; ++g) {
      int e = b*32 + g*4 + j;
      int eL = e < E_EDGES ? e : E_EDGES-1;
      if (m < 8) sBC[j*8+m] = bc[(size_t)eL*8 + m];
      float t = sB[m];
      #pragma unroll
      for (int bb = 0; bb < 8; ++bb) t += sBC[j*8+bb]*sW1[bb*64 + m];
      sH[j*64+m] = siluf(t);
      float a0 = sb0[m], a1 = sb1[m];
      for (int mm = 0; mm < 64; ++mm) {
        float hv = sH[j*64+mm];
        a0 += hv*sM0[mm*64 + m];
        a1 += hv*sM1[mm*64 + m];
      }
      if (e < E_EDGES) {
        q0[(size_t)e*64 + m] = siluf(a0);
        q1b[(size_t)e*64 + m] = __float2bfloat16(siluf(a1));
      }
    }
  } else {
    int bb = b - 1563;
    const int col = (bb % 14)*256 + tid;
    const int nb = (bb / 14)*8;
    float* ns = smem;
    for (int i = tid; i < 512; i += 256)
      ns[i] = node0[(size_t)(nb + (i>>6))*64 + (i&63)];
    __syncthreads();
    float acc[8] = {0,0,0,0,0,0,0,0};
    for (int u = 0; u < 64; ++u) {
      float wv = W0r[(size_t)u*3584 + col];
      #pragma unroll
      for (int n = 0; n < 8; ++n) acc[n] += ns[n*64+u]*wv;
    }
    #pragma unroll
    for (int n = 0; n < 8; ++n)
      G0[(size_t)(nb+n)*3584 + col] = __float2bfloat16(acc[n]);
  }
}

// ================= layer-0 message: 2 edges per wave =================
__global__ void __launch_bounds__(256) k_msg0b(
    const float* __restrict__ q0, const bf16* __restrict__ G0,
    const float* __restrict__ shb, const int* __restrict__ ei,
    float* __restrict__ agg0) {
  __shared__ float sq[8][64];
  const int tid = threadIdx.x;
  const int wave = tid >> 6;
  const int lane = tid & 63;
  const int ebase = blockIdx.x*8;
  for (int i = tid; i < 512; i += 256)
    sq[i>>6][i&63] = q0[(size_t)(ebase + (i>>6))*64 + (i&63)];
  __syncthreads();
  const int e0 = ebase + wave*2, e1 = e0 + 1;
  const int src0 = ei[e0], src1 = ei[e1];
  const int dst0 = ei[E_EDGES + e0], dst1 = ei[E_EDGES + e1];
  float z0 = 0.f, z1 = 0.f;
  if (lane < 56) {
    const short* gp0 = (const short*)G0 + (size_t)src0*3584 + lane*64;
    const short* gp1 = (const short*)G0 + (size_t)src1*3584 + lane*64;
    short8 ga[8], gb[8];
    #pragma unroll
    for (int hb = 0; hb < 8; ++hb) { ga[hb] = *(const short8*)(gp0 + hb*8);
                                     gb[hb] = *(const short8*)(gp1 + hb*8); }
    #pragma unroll
    for (int hb = 0; hb < 8; ++hb) {
      #pragma unroll
      for (int jj = 0; jj < 8; ++jj) {
        z0 += sq[wave*2  ][hb*8+jj]*us2f((unsigned short)ga[hb][jj]);
        z1 += sq[wave*2+1][hb*8+jj]*us2f((unsigned short)gb[hb][jj]);
      }
    }
  }
  const float c = 0.125f * 0.3162277660168379f;
  #pragma unroll
  for (int pass = 0; pass < 2; ++pass) {
    float z = pass ? z1 : z0;
    int e = pass ? e1 : e0;
    float* ap = agg0 + (size_t)(pass ? dst1 : dst0)*120;
    const float* sh = shb + (size_t)e*12;
    if (lane < 32) {
      atomicAdd(ap + lane, z*c);
    } else if (lane < 48) {
      int v = lane - 32;
      #pragma unroll
      for (int k = 0; k < 3; ++k) atomicAdd(ap + 32 + v*3 + k, z*sh[1+k]*c);
    } else if (lane < 56) {
      int v = lane - 48;
      #pragma unroll
      for (int k = 0; k < 5; ++k) atomicAdd(ap + 80 + v*5 + k, z*sh[4+k]*c);
    }
  }
}

__global__ void k_node1(const float* __restrict__ agg0, const float* __restrict__ node0,
                        const float* __restrict__ sc00, float* __restrict__ node1) {
  __shared__ float n0[64];
  int n = blockIdx.x, tid = threadIdx.x;
  if (tid < 64) n0[tid] = node0[(size_t)n*64 + tid];
  __syncthreads();
  if (tid >= 120) return;
  float v = agg0[(size_t)n*120 + tid];
  if (tid < 32) {
    float s = 0.f;
    for (int u = 0; u < 64; ++u) s += n0[u]*sc00[u*32 + tid];
    v += s * 0.125f;
    v = siluf(v);
  }
  node1[(size_t)n*120 + tid] = v;
}

// ================= layer-1 w GEMM (MFMA bf16) =================
__global__ void __launch_bounds__(256) k_wgemm(
    const bf16* __restrict__ q1b, const bf16* __restrict__ W2t,
    bf16* __restrict__ wout, int e0, int nE) {
  __shared__ short lds[4][32*64];
  const int tid = threadIdx.x;
  const int wid = tid >> 6, lane = tid & 63;
  const int nt = blockIdx.x*4 + wid;
  const int r0 = blockIdx.y*32;
  const int row16 = lane & 15, quad = lane >> 4;

  short8 a[2][2];
  #pragma unroll
  for (int mi = 0; mi < 2; ++mi) {
    int r = r0 + mi*16 + row16;
    int rg = e0 + ((r < nE) ? r : 0);
    const short* ap = (const short*)q1b + (size_t)rg*64 + quad*8;
    a[mi][0] = *(const short8*)(ap);
    a[mi][1] = *(const short8*)(ap + 32);
  }
  if (nt < 54) {
    f32x4 acc[4][2] = {};
    #pragma unroll
    for (int ni = 0; ni < 4; ++ni) {
      int col = nt*64 + ni*16 + row16;
      const short* bp = (const short*)W2t + (size_t)col*64 + quad*8;
      short8 b0 = *(const short8*)(bp);
      short8 b1 = *(const short8*)(bp + 32);
      #pragma unroll
      for (int mi = 0; mi < 2; ++mi) {
        acc[ni][mi] = __builtin_amdgcn_mfma_f32_16x16x32_bf16(a[mi][0], b0, acc[ni][mi], 0,0,0);
        acc[ni][mi] = __builtin_amdgcn_mfma_f32_16x16x32_bf16(a[mi][1], b1, acc[ni][mi], 0,0,0);
      }
    }
    #pragma unroll
    for (int ni = 0; ni < 4; ++ni)
      #pragma unroll
      for (int mi = 0; mi < 2; ++mi)
        #pragma unroll
        for (int rr = 0; rr < 4; ++rr) {
          bf16 hv = __float2bfloat16(acc[ni][mi][rr]);
          lds[wid][(mi*16 + quad*4 + rr)*64 + ni*16 + row16] = *(short*)&hv;
        }
  }
  __syncthreads();
  if (nt < 54) {
    #pragma unroll
    for (int it = 0; it < 4; ++it) {
      int unit = it*64 + lane;
      int rrow = unit >> 3;
      int cu = (unit & 7) * 8;
      int r = r0 + rrow;
      if (r < nE)
        *(uint4*)((short*)wout + (size_t)r*3456 + nt*64 + cu) =
            *(const uint4*)&lds[wid][rrow*64 + cu];
    }
  }
}

// ================= layer-1 consume v4: one wave/edge; w via global short8; reg accum =================
__global__ void __launch_bounds__(256) k_tp4(
    const bf16* __restrict__ wch, const float* __restrict__ node1,
    const float* __restrict__ shb, const int* __restrict__ ei,
    int e0, int nE, float* __restrict__ agg1) {
  __shared__ float tl[4][592];
  __shared__ float xl[4][120];
  __shared__ float shl[4][12];
  const int tid = threadIdx.x;
  const int wv = tid >> 6, lane = tid & 63;
  int elr = blockIdx.x*4 + wv;
  const bool live = elr < nE;
  const int el = live ? elr : nE-1;
  const int eg = e0 + el;
  const int src = ei[eg], dst = ei[E_EDGES + eg];

  for (int i = lane; i < 120; i += 64) xl[wv][i] = node1[(size_t)src*120 + i];
  if (lane < 12) shl[wv][lane] = shb[(size_t)eg*12 + lane];
  __syncthreads();

  {
    const float* x  = xl[wv];
    const float* sh = shl[wv];
    const float A = 0.3162277660168379f, Bc = 0.1825741858350554f, B2 = 0.3651483716701107f;
    const int I_[11] = {0,2,0,1,1,2, 0,1,2, 0,2};
    const int J_[11] = {2,0,1,0,2,1, 0,1,2, 0,2};
    const int K_[11] = {0,0,1,1,3,3, 2,2,2, 4,4};
    const float V_[11] = {A,A,A,A,A,A, -Bc,B2,-Bc, -A,A};
    for (int idx = lane; idx < 592; idx += 64) {
      float t = 0.0f;
      if (idx < 32)       { t = x[idx] * 0.1336306209562122f; }
      else if (idx < 128) { int j = idx-32,  u=j/3, k=j-u*3; t = x[u]*sh[1+k] * 0.1178511301977579f; }
      else if (idx < 288) { int j = idx-128, u=j/5, k=j-u*5; t = x[u]*sh[4+k] * 0.125f; }
      else if (idx < 336) { int j = idx-288, u=j/3, k=j-u*3; t = x[32+u*3+k] * 0.1178511301977579f; }
      else if (idx < 352) { int u = idx-336;
        t = (x[32+u*3]*sh[1] + x[32+u*3+1]*sh[2] + x[32+u*3+2]*sh[3]) * 0.0771516749810460f; }
      else if (idx < 432) { int j = idx-352, u=j/5, k=j-u*5;
        float s = 0.f;
        #pragma unroll
        for (int q = 0; q < 11; ++q) if (K_[q] == k)
          s += V_[q]*x[32+u*3+I_[q]]*sh[1+J_[q]];
        t = s * 0.2795084971874737f; }
      else if (idx < 480) { int j = idx-432, u=j/3, k=j-u*3;
        float s = 0.f;
        #pragma unroll
        for (int q = 0; q < 11; ++q) if (J_[q] == k)
          s += V_[q]*x[32+u*3+I_[q]]*sh[4+K_[q]];
        t = s * 0.2041241452319315f; }
      else if (idx < 520) { int j = idx-480, u=j/5, k=j-u*5; t = x[80+u*5+k] * 0.125f; }
      else if (idx < 544) { int j = idx-520, u=j/3, k=j-u*3;
        float s = 0.f;
        #pragma unroll
        for (int q = 0; q < 11; ++q) if (J_[q] == k)
          s += V_[q]*x[80+u*5+K_[q]]*sh[1+I_[q]];
        t = s * 0.2041241452319315f; }
      else if (idx < 552) { int u = idx-544;
        float s = 0.f;
        #pragma unroll
        for (int q = 0; q < 5; ++q) s += x[80+u*5+q]*sh[4+q];
        t = s * 0.0597614304667197f; }
      else { int j = idx-552, u=j/5, k=j-u*5;
        const float P = 0.2390457218668787f, Q = 0.2070196678027063f, R = 0.1195228609334394f;
        const int I2_[25] = {0,0,2, 0,0,1,1,3,3, 1,1,2, 1,1,4, 2, 2,3,3, 2,4,4, 3,3,4};
        const int J2_[25] = {0,2,0, 1,3,0,3,0,1, 1,2,1, 1,4,1, 2, 3,2,3, 4,2,4, 3,4,3};
        const int K2_[25] = {2,0,0, 3,1,3,0,1,0, 2,1,1, 4,1,1, 2, 3,3,2, 4,4,2, 4,3,3};
        const float V2_[25] = {P,P,P, -Q,-Q,-Q,-Q,-Q,-Q, -R,-R,-R, Q,Q,Q, -P,
                               -R,-R,-R, P,P,P, -Q,-Q,-Q};
        float s = 0.f;
        #pragma unroll
        for (int q = 0; q < 25; ++q) if (K2_[q] == k)
          s += V2_[q]*x[80+u*5+I2_[q]]*sh[4+J2_[q]];
        t = s * 0.2795084971874737f; }
      tl[wv][idx] = t;
    }
  }
  __syncthreads();

  // consume: w in per-path [v][u] layout -> u-contiguous short8 global loads
  const short* wrow = (const short*)wch + (size_t)el*3456;
  const float* t = tl[wv];
  float r0 = 0.f, r1 = 0.f, r2 = 0.f;
  #define PATHC(OFF, M1C, NKC, TOFFC, REG)                                  \
    { int v = lane / (NKC), k = lane - v*(NKC);                             \
      const short* wp = wrow + (OFF) + v*(M1C);                             \
      _Pragma("unroll")                                                     \
      for (int ub = 0; ub < (M1C)/8; ++ub) {                                \
        short8 w8 = *(const short8*)(wp + ub*8);                            \
        _Pragma("unroll")                                                   \
        for (int r = 0; r < 8; ++r)                                         \
          REG += us2f((unsigned short)w8[r]) * t[(TOFFC)+(ub*8+r)*(NKC)+k]; \
      } }
  if (lane < 32) {          // l=0 outputs
    PATHC(0,    32, 1, 0,   r0)
    PATHC(2048, 16, 1, 336, r0)
    PATHC(3136,  8, 1, 544, r0)
  }
  if (lane < 48) {          // l=1 outputs
    PATHC(1024, 32, 3, 32,  r1)
    PATHC(1792, 16, 3, 288, r1)
    PATHC(2688, 16, 3, 432, r1)
    PATHC(3008,  8, 3, 520, r1)
  }
  if (lane < 40) {          // l=2 outputs
    PATHC(1536, 32, 5, 128, r2)
    PATHC(2560, 16, 5, 352, r2)
    PATHC(2944,  8, 5, 480, r2)
    PATHC(3392,  8, 5, 552, r2)
  }
  #undef PATHC

  if (live) {
    const float s = 0.3162277660168379f;
    float* ap = agg1 + (size_t)dst*120;
    if (lane < 32) atomicAdd(ap + lane, r0*s);
    if (lane < 48) atomicAdd(ap + 32 + lane, r1*s);
    if (lane < 40) atomicAdd(ap + 80 + lane, r2*s);
  }
}

__global__ void k_out(const float* __restrict__ agg1, const float* __restrict__ node1,
                      const float* __restrict__ sc0e, const float* __restrict__ sc1o,
                      const float* __restrict__ sc2e, float* __restrict__ out) {
  __shared__ float x[120];
  int n = blockIdx.x, tid = threadIdx.x;
  if (tid < 120) x[tid] = node1[(size_t)n*120 + tid];
  __syncthreads();
  if (tid >= 120) return;
  float v = agg1[(size_t)n*120 + tid];
  if (tid < 32) {
    float s = 0.f;
    for (int u = 0; u < 32; ++u) s += x[u]*sc0e[u*32 + tid];
    v += s * 0.1767766952966369f;
  } else if (tid < 80) {
    int jj = tid - 32, vv = jj/3, k = jj - vv*3;
    float s = 0.f;
    for (int u = 0; u < 16; ++u) s += x[32 + u*3 + k]*sc1o[u*16 + vv];
    v += s * 0.25f;
  } else {
    int jj = tid - 80, vv = jj/5, k = jj - vv*5;
    float s = 0.f;
    for (int u = 0; u < 8; ++u) s += x[80 + u*5 + k]*sc2e[u*8 + vv];
    v += s * 0.3535533905932738f;
  }
  out[(size_t)n*120 + tid] = v;
}

// ---------------- launch ----------------
extern "C" void kernel_launch(void* const* d_in, const int* in_sizes, int n_in,
                              void* d_out, int out_size, void* d_ws, size_t ws_size,
                              hipStream_t stream) {
  const float* embed   = (const float*)d_in[1];
  const float* rad_w1  = (const float*)d_in[2];
  const float* rad_b1  = (const float*)d_in[3];
  const float* rad_w2  = (const float*)d_in[4];
  const float* rad_b2  = (const float*)d_in[5];
  const float* wnn0_w1 = (const float*)d_in[6];
  const float* wnn0_w2 = (const float*)d_in[7];
  const float* wnn1_w1 = (const float*)d_in[8];
  const float* wnn1_w2 = (const float*)d_in[9];
  const float* sc0_0e  = (const float*)d_in[10];
  const float* sc1_0e  = (const float*)d_in[11];
  const float* sc1_1o  = (const float*)d_in[12];
  const float* sc1_2e  = (const float*)d_in[13];
  const float* edge_vec = (const float*)d_in[14];
  const float* edge_len = (const float*)d_in[15];
  const int*  anum    = (const int*)d_in[16];
  const int*  ei      = (const int*)d_in[17];

  float* ws = (float*)d_ws;
  float* shbuf = ws;                      // 600000
  float* bc    = ws + 600000;             // 400000
  bf16*  q1b   = (bf16*)(ws + 1000000);   // 1.6M f-slots
  float* node0 = ws + 2600000;            // 320000
  float* W0r   = ws + 2920000;            // 229376
  bf16*  W2t   = (bf16*)(ws + 3149376);   // 110592 f-slots
  float* M0    = ws + 3259968;            // 4096
  float* M1    = ws + 3264064;            // 4096
  float* bias0 = ws + 3268160;            // 64
  float* bias1 = ws + 3268224;            // 64
  float* agg0  = ws + 3268288;            // 600000
  float* agg1  = ws + 3868288;            // 600000 (adjacent -> one memset)
  float* node1 = ws + 4468288;            // 600000
  float* q0    = ws + 5068288;            // 3200000
  bf16*  G0    = (bf16*)(ws + 8268288);   // 8.96M f-slots -> base end 17228288 (68.9 MB)

  // layer-1 w buffer: largest chunk that fits AND stays L3-resident (prefer 25000)
  long long CH; bf16* wbuf;
  const size_t base_end = 17228288ull;
  if      (ws_size >= (base_end + 43200000ull)*4) { CH = 25000; wbuf = (bf16*)(ws + base_end); }
  else if (ws_size >= (base_end + 21600000ull)*4) { CH = 12500; wbuf = (bf16*)(ws + base_end); }
  else                                            { CH = 6250;  wbuf = (bf16*)(ws + 5068288); } // alias q0+G0

  hipMemsetAsync(agg0, 0, 1200000*sizeof(float), stream);   // agg0 + agg1

  k_setup<<<3222, 256, 0, stream>>>(edge_vec, edge_len, shbuf, bc,
                                    rad_w2, rad_b2, wnn0_w1, wnn1_w1, M0, M1, bias0, bias1,
                                    embed, anum, node0,
                                    wnn0_w2, W0r, wnn1_w2, W2t);
  k_mid<<<1563 + 8750, 256, 0, stream>>>(bc, rad_w1, rad_b1, M0, M1, bias0, bias1,
                                         q0, q1b, node0, W0r, G0);
  k_msg0b<<<E_EDGES/8, 256, 0, stream>>>(q0, G0, shbuf, ei, agg0);
  k_node1<<<NN, 128, 0, stream>>>(agg0, node0, sc0_0e, node1);

  for (long long e0 = 0; e0 < E_EDGES; e0 += CH) {
    k_wgemm<<<dim3(14, (unsigned)((CH+31)/32), 1), 256, 0, stream>>>(q1b, W2t, wbuf, (int)e0, (int)CH);
    k_tp4<<<(unsigned)((CH+3)/4), 256, 0, stream>>>(wbuf, node1, shbuf, ei, (int)e0, (int)CH, agg1);
  }
  k_out<<<NN, 128, 0, stream>>>(agg1, node1, sc1_0e, sc1_1o, sc1_2e, (float*)d_out);
}

// Round 10
// 590.985 us; speedup vs baseline: 2.1107x; 1.0167x over previous
//
#include <hip/hip_runtime.h>
#include <hip/hip_bf16.h>
#include <math.h>

#define E_EDGES 50000
#define NN 5000

typedef __hip_bfloat16 bf16;
typedef __attribute__((ext_vector_type(8))) short short8;
typedef __attribute__((ext_vector_type(4))) float f32x4;

__device__ __forceinline__ float b2f(bf16 v) { return __bfloat162float(v); }
__device__ __forceinline__ float siluf(float x) { return x / (1.0f + __expf(-x)); }
__device__ __forceinline__ float us2f(unsigned short u) {
  union { unsigned int i; float f; } c; c.i = ((unsigned int)u) << 16; return c.f;
}

// ================= merged setup: prep(+hist) | fuse | embed | w0r | w2t(permuted) =================
__global__ void __launch_bounds__(256) k_setup(
    const float* __restrict__ evec, const float* __restrict__ elen,
    float* __restrict__ shb, float* __restrict__ bc,
    const float* __restrict__ w2, const float* __restrict__ b2,
    const float* __restrict__ w01, const float* __restrict__ w11,
    float* __restrict__ M0, float* __restrict__ M1,
    float* __restrict__ bias0, float* __restrict__ bias1,
    const float* __restrict__ emb, const int* __restrict__ an,
    float* __restrict__ node0,
    const float* __restrict__ w0, float* __restrict__ W0r,
    const float* __restrict__ w1w2, bf16* __restrict__ W2t,
    const int* __restrict__ ei, int* __restrict__ hist) {
  const int b = blockIdx.x, tid = threadIdx.x;
  if (b < 196) {                      // ---- prep (sh + basis*cutoff) + src histogram
    int e = b*256 + tid;
    if (e >= E_EDGES) return;
    atomicAdd(&hist[ei[e]], 1);
    float x = evec[3*e+0], y = evec[3*e+1], z = evec[3*e+2];
    float r = elen[e];
    float inv = 1.0f / (r + 1e-8f);
    float ux = x*inv, uy = y*inv, uz = z*inv;
    const float s3 = 1.7320508075688772f, s5 = 2.2360679774997896f, s15 = 3.8729833462074170f;
    float* sh = shb + (size_t)e*12;
    sh[0] = 1.0f;
    sh[1] = s3*uy; sh[2] = s3*uz; sh[3] = s3*ux;
    sh[4] = s15*ux*uy; sh[5] = s15*uy*uz; sh[6] = 0.5f*s5*(3.0f*uz*uz - 1.0f);
    sh[7] = s15*ux*uz; sh[8] = 0.5f*s15*(ux*ux - uy*uy);
    sh[9] = 0.f; sh[10] = 0.f; sh[11] = 0.f;
    float rr = fmaxf(r, 1e-8f);
    const float pi = 3.14159265358979f;
    float xr = r * 0.2f;
    float cut = (xr < 1.0f) ? 0.5f*(1.0f + cosf(pi*xr)) : 0.0f;
    float fb = pi * 0.2f;
    for (int k = 1; k <= 8; ++k)
      bc[(size_t)e*8 + (k-1)] = sinf(fb*(float)k*r)/rr * cut;
  } else if (b < 212) {               // ---- fuse rad_w2 into wnn*_w1
    int i = (b-196)*256 + tid;        // 4096
    int hh = i >> 6, c = i & 63;
    float a0 = 0.f, a1 = 0.f;
    for (int j = 0; j < 64; ++j) {
      float wv = w2[hh*64 + j];
      a0 += wv * w01[j*64 + c];
      a1 += wv * w11[j*64 + c];
    }
    M0[hh*64 + c] = a0;
    M1[hh*64 + c] = a1;
    if (hh == 0) {
      float s0 = 0.f, s1 = 0.f;
      for (int j = 0; j < 64; ++j) {
        s0 += b2[j] * w01[j*64 + c];
        s1 += b2[j] * w11[j*64 + c];
      }
      bias0[c] = s0;
      bias1[c] = s1;
    }
  } else if (b < 1462) {              // ---- embed (320000 exact)
    int i = (b-212)*256 + tid;
    int n = i >> 6, c = i & 63;
    node0[i] = emb[an[n]*64 + c];
  } else if (b < 2358) {              // ---- w0r reorder -> [u][h*56+vp] (229376 exact)
    int idx = (b-1462)*256 + tid;
    int u = idx / 3584, r = idx - u*3584;
    int hh = r / 56, vp = r - hh*56;
    int boff, m3, v;
    if (vp < 32)      { boff = 0;    m3 = 32; v = vp; }
    else if (vp < 48) { boff = 2048; m3 = 16; v = vp - 32; }
    else              { boff = 3072; m3 = 8;  v = vp - 48; }
    W0r[idx] = w0[hh*3584 + boff + u*m3 + v];
  } else {                            // ---- w2t transpose + per-path [v][u] permute
    int idx = (b-2358)*256 + tid;     // 221184 exact
    int nn = idx >> 6, k = idx & 63;
    int p, loc;
    if (nn < 1024)      { p=0;  loc=nn;      }
    else if (nn < 1536) { p=1;  loc=nn-1024; }
    else if (nn < 1792) { p=2;  loc=nn-1536; }
    else if (nn < 2048) { p=3;  loc=nn-1792; }
    else if (nn < 2560) { p=4;  loc=nn-2048; }
    else if (nn < 2688) { p=5;  loc=nn-2560; }
    else if (nn < 2944) { p=6;  loc=nn-2688; }
    else if (nn < 3008) { p=7;  loc=nn-2944; }
    else if (nn < 3136) { p=8;  loc=nn-3008; }
    else if (nn < 3392) { p=9;  loc=nn-3136; }
    else                { p=10; loc=nn-3392; }
    const int M1s[11] = {32,32,32,16,16,16,16,8,8,8,8};
    const int M3s[11] = {32,16,8,16,32,8,16,8,16,32,8};
    int m1 = M1s[p], m3 = M3s[p];
    int v = loc / m1, u = loc - v*m1;
    int src = (nn - loc) + u*m3 + v;
    W2t[idx] = __float2bfloat16(w1w2[(size_t)k*3456 + src]);
  }
}

// ================= merged mid: rad4 | g0 | scan =================
__global__ void __launch_bounds__(256) k_mid(
    const float* __restrict__ bc,
    const float* __restrict__ w1, const float* __restrict__ b1,
    const float* __restrict__ M0, const float* __restrict__ M1,
    const float* __restrict__ bias0, const float* __restrict__ bias1,
    float* __restrict__ q0, bf16* __restrict__ q1b,
    const float* __restrict__ node0, const float* __restrict__ W0r,
    bf16* __restrict__ G0,
    const int* __restrict__ hist, int* __restrict__ start) {
  __shared__ float smem[9184];
  const int tid = threadIdx.x;
  const int b = blockIdx.x;
  if (b < 1563) {
    float* sM0 = smem;          float* sM1 = smem + 4096;
    float* sW1 = smem + 8192;   float* sB  = smem + 8704;
    float* sb0 = smem + 8768;   float* sb1 = smem + 8832;
    float* sH  = smem + 8896;   float* sBC = smem + 9152;
    const int j = tid >> 6, m = tid & 63;
    for (int i = tid; i < 4096; i += 256) { sM0[i] = M0[i]; sM1[i] = M1[i]; }
    for (int i = tid; i < 512; i += 256) sW1[i] = w1[i];
    if (tid < 64) { sB[tid] = b1[tid]; sb0[tid] = bias0[tid]; sb1[tid] = bias1[tid]; }
    __syncthreads();
    for (int g = 0; g < 8; ++g) {
      int e = b*32 + g*4 + j;
      int eL = e < E_EDGES ? e : E_EDGES-1;
      if (m < 8) sBC[j*8+m] = bc[(size_t)eL*8 + m];
      float t = sB[m];
      #pragma unroll
      for (int bb = 0; bb < 8; ++bb) t += sBC[j*8+bb]*sW1[bb*64 + m];
      sH[j*64+m] = siluf(t);
      float a0 = sb0[m], a1 = sb1[m];
      for (int mm = 0; mm < 64; ++mm) {
        float hv = sH[j*64+mm];
        a0 += hv*sM0[mm*64 + m];
        a1 += hv*sM1[mm*64 + m];
      }
      if (e < E_EDGES) {
        q0[(size_t)e*64 + m] = siluf(a0);
        q1b[(size_t)e*64 + m] = __float2bfloat16(siluf(a1));
      }
    }
  } else if (b < 1563 + 8750) {
    int bb = b - 1563;
    const int col = (bb % 14)*256 + tid;
    const int nb = (bb / 14)*8;
    float* ns = smem;
    for (int i = tid; i < 512; i += 256)
      ns[i] = node0[(size_t)(nb + (i>>6))*64 + (i&63)];
    __syncthreads();
    float acc[8] = {0,0,0,0,0,0,0,0};
    for (int u = 0; u < 64; ++u) {
      float wv = W0r[(size_t)u*3584 + col];
      #pragma unroll
      for (int n = 0; n < 8; ++n) acc[n] += ns[n*64+u]*wv;
    }
    #pragma unroll
    for (int n = 0; n < 8; ++n)
      G0[(size_t)(nb+n)*3584 + col] = __float2bfloat16(acc[n]);
  } else {
    // ---- exclusive scan: hist[0..5000) -> start[0..5000]
    int* sp = (int*)smem;
    int base = tid*20;
    int localsum = 0;
    for (int i = 0; i < 20; ++i) { int jj = base+i; localsum += (jj < NN) ? hist[jj] : 0; }
    sp[tid] = localsum;
    __syncthreads();
    if (tid == 0) {
      int acc = 0;
      for (int i = 0; i < 256; ++i) { int t = sp[i]; sp[i] = acc; acc += t; }
    }
    __syncthreads();
    int run = sp[tid];
    for (int i = 0; i < 20; ++i) {
      int jj = base+i;
      if (jj < NN) { start[jj] = run; run += hist[jj]; }
    }
    if (tid == 255) start[NN] = run;
  }
}

// ================= CSR scatter: perm = edges sorted by src =================
__global__ void k_scat(const int* __restrict__ ei, const int* __restrict__ start,
                       int* __restrict__ cursor, int* __restrict__ perm) {
  int e = blockIdx.x*256 + threadIdx.x;
  if (e >= E_EDGES) return;
  int src = ei[e];
  int pos = start[src] + atomicAdd(&cursor[src], 1);
  perm[pos] = e;
}

// ================= layer-0 message: per-node; G0 row staged in LDS once =================
__global__ void __launch_bounds__(256) k_msg0c(
    const float* __restrict__ q0, const bf16* __restrict__ G0,
    const float* __restrict__ shb, const int* __restrict__ ei,
    const int* __restrict__ start, const int* __restrict__ perm,
    float* __restrict__ agg0) {
  __shared__ uint4 g4[448];          // G0 row n: [h*56+vp], 3584 bf16
  __shared__ float sq[4][64];
  const int n = blockIdx.x;
  const int tid = threadIdx.x;
  const int wv = tid >> 6, lane = tid & 63;
  const uint4* gr = (const uint4*)(G0 + (size_t)n*3584);
  for (int i = tid; i < 448; i += 256) g4[i] = gr[i];
  const int s0 = start[n], s1 = start[n+1];
  __syncthreads();
  const short* gs = (const short*)g4;
  const float c = 0.125f * 0.3162277660168379f;
  for (int base = s0; base < s1; base += 4) {
    int idx = base + wv;
    if (idx < s1) {
      int e = perm[idx];
      sq[wv][lane] = q0[(size_t)e*64 + lane];   // intra-wave LDS dep: compiler waits
      float z = 0.f;
      if (lane < 56) {
        #pragma unroll
        for (int h = 0; h < 64; ++h)
          z += sq[wv][h]*us2f((unsigned short)gs[h*56 + lane]);  // bank: 28h+lane/2 -> 2-way free
      }
      int dst = ei[E_EDGES + e];
      float* ap = agg0 + (size_t)dst*120;
      const float* sh = shb + (size_t)e*12;
      if (lane < 32) {
        atomicAdd(ap + lane, z*c);
      } else if (lane < 48) {
        int v = lane - 32;
        #pragma unroll
        for (int k = 0; k < 3; ++k) atomicAdd(ap + 32 + v*3 + k, z*sh[1+k]*c);
      } else if (lane < 56) {
        int v = lane - 48;
        #pragma unroll
        for (int k = 0; k < 5; ++k) atomicAdd(ap + 80 + v*5 + k, z*sh[4+k]*c);
      }
    }
  }
}

__global__ void k_node1(const float* __restrict__ agg0, const float* __restrict__ node0,
                        const float* __restrict__ sc00, float* __restrict__ node1) {
  __shared__ float n0[64];
  int n = blockIdx.x, tid = threadIdx.x;
  if (tid < 64) n0[tid] = node0[(size_t)n*64 + tid];
  __syncthreads();
  if (tid >= 120) return;
  float v = agg0[(size_t)n*120 + tid];
  if (tid < 32) {
    float s = 0.f;
    for (int u = 0; u < 64; ++u) s += n0[u]*sc00[u*32 + tid];
    v += s * 0.125f;
    v = siluf(v);
  }
  node1[(size_t)n*120 + tid] = v;
}

// ================= layer-1 w GEMM (MFMA bf16) =================
__global__ void __launch_bounds__(256) k_wgemm(
    const bf16* __restrict__ q1b, const bf16* __restrict__ W2t,
    bf16* __restrict__ wout, int e0, int nE) {
  __shared__ short lds[4][32*64];
  const int tid = threadIdx.x;
  const int wid = tid >> 6, lane = tid & 63;
  const int nt = blockIdx.x*4 + wid;
  const int r0 = blockIdx.y*32;
  const int row16 = lane & 15, quad = lane >> 4;

  short8 a[2][2];
  #pragma unroll
  for (int mi = 0; mi < 2; ++mi) {
    int r = r0 + mi*16 + row16;
    int rg = e0 + ((r < nE) ? r : 0);
    const short* ap = (const short*)q1b + (size_t)rg*64 + quad*8;
    a[mi][0] = *(const short8*)(ap);
    a[mi][1] = *(const short8*)(ap + 32);
  }
  if (nt < 54) {
    f32x4 acc[4][2] = {};
    #pragma unroll
    for (int ni = 0; ni < 4; ++ni) {
      int col = nt*64 + ni*16 + row16;
      const short* bp = (const short*)W2t + (size_t)col*64 + quad*8;
      short8 b0 = *(const short8*)(bp);
      short8 b1 = *(const short8*)(bp + 32);
      #pragma unroll
      for (int mi = 0; mi < 2; ++mi) {
        acc[ni][mi] = __builtin_amdgcn_mfma_f32_16x16x32_bf16(a[mi][0], b0, acc[ni][mi], 0,0,0);
        acc[ni][mi] = __builtin_amdgcn_mfma_f32_16x16x32_bf16(a[mi][1], b1, acc[ni][mi], 0,0,0);
      }
    }
    #pragma unroll
    for (int ni = 0; ni < 4; ++ni)
      #pragma unroll
      for (int mi = 0; mi < 2; ++mi)
        #pragma unroll
        for (int rr = 0; rr < 4; ++rr) {
          bf16 hv = __float2bfloat16(acc[ni][mi][rr]);
          lds[wid][(mi*16 + quad*4 + rr)*64 + ni*16 + row16] = *(short*)&hv;
        }
  }
  __syncthreads();
  if (nt < 54) {
    #pragma unroll
    for (int it = 0; it < 4; ++it) {
      int unit = it*64 + lane;
      int rrow = unit >> 3;
      int cu = (unit & 7) * 8;
      int r = r0 + rrow;
      if (r < nE)
        *(uint4*)((short*)wout + (size_t)r*3456 + nt*64 + cu) =
            *(const uint4*)&lds[wid][rrow*64 + cu];
    }
  }
}

// ================= layer-1 consume: one wave/edge; w via global short8; reg accum =================
__global__ void __launch_bounds__(256) k_tp4(
    const bf16* __restrict__ wch, const float* __restrict__ node1,
    const float* __restrict__ shb, const int* __restrict__ ei,
    int e0, int nE, float* __restrict__ agg1) {
  __shared__ float tl[4][592];
  __shared__ float xl[4][120];
  __shared__ float shl[4][12];
  const int tid = threadIdx.x;
  const int wv = tid >> 6, lane = tid & 63;
  int elr = blockIdx.x*4 + wv;
  const bool live = elr < nE;
  const int el = live ? elr : nE-1;
  const int eg = e0 + el;
  const int src = ei[eg], dst = ei[E_EDGES + eg];

  for (int i = lane; i < 120; i += 64) xl[wv][i] = node1[(size_t)src*120 + i];
  if (lane < 12) shl[wv][lane] = shb[(size_t)eg*12 + lane];
  __syncthreads();

  {
    const float* x  = xl[wv];
    const float* sh = shl[wv];
    const float A = 0.3162277660168379f, Bc = 0.1825741858350554f, B2 = 0.3651483716701107f;
    const int I_[11] = {0,2,0,1,1,2, 0,1,2, 0,2};
    const int J_[11] = {2,0,1,0,2,1, 0,1,2, 0,2};
    const int K_[11] = {0,0,1,1,3,3, 2,2,2, 4,4};
    const float V_[11] = {A,A,A,A,A,A, -Bc,B2,-Bc, -A,A};
    for (int idx = lane; idx < 592; idx += 64) {
      float t = 0.0f;
      if (idx < 32)       { t = x[idx] * 0.1336306209562122f; }
      else if (idx < 128) { int j = idx-32,  u=j/3, k=j-u*3; t = x[u]*sh[1+k] * 0.1178511301977579f; }
      else if (idx < 288) { int j = idx-128, u=j/5, k=j-u*5; t = x[u]*sh[4+k] * 0.125f; }
      else if (idx < 336) { int j = idx-288, u=j/3, k=j-u*3; t = x[32+u*3+k] * 0.1178511301977579f; }
      else if (idx < 352) { int u = idx-336;
        t = (x[32+u*3]*sh[1] + x[32+u*3+1]*sh[2] + x[32+u*3+2]*sh[3]) * 0.0771516749810460f; }
      else if (idx < 432) { int j = idx-352, u=j/5, k=j-u*5;
        float s = 0.f;
        #pragma unroll
        for (int q = 0; q < 11; ++q) if (K_[q] == k)
          s += V_[q]*x[32+u*3+I_[q]]*sh[1+J_[q]];
        t = s * 0.2795084971874737f; }
      else if (idx < 480) { int j = idx-432, u=j/3, k=j-u*3;
        float s = 0.f;
        #pragma unroll
        for (int q = 0; q < 11; ++q) if (J_[q] == k)
          s += V_[q]*x[32+u*3+I_[q]]*sh[4+K_[q]];
        t = s * 0.2041241452319315f; }
      else if (idx < 520) { int j = idx-480, u=j/5, k=j-u*5; t = x[80+u*5+k] * 0.125f; }
      else if (idx < 544) { int j = idx-520, u=j/3, k=j-u*3;
        float s = 0.f;
        #pragma unroll
        for (int q = 0; q < 11; ++q) if (J_[q] == k)
          s += V_[q]*x[80+u*5+K_[q]]*sh[1+I_[q]];
        t = s * 0.2041241452319315f; }
      else if (idx < 552) { int u = idx-544;
        float s = 0.f;
        #pragma unroll
        for (int q = 0; q < 5; ++q) s += x[80+u*5+q]*sh[4+q];
        t = s * 0.0597614304667197f; }
      else { int j = idx-552, u=j/5, k=j-u*5;
        const float P = 0.2390457218668787f, Q = 0.2070196678027063f, R = 0.1195228609334394f;
        const int I2_[25] = {0,0,2, 0,0,1,1,3,3, 1,1,2, 1,1,4, 2, 2,3,3, 2,4,4, 3,3,4};
        const int J2_[25] = {0,2,0, 1,3,0,3,0,1, 1,2,1, 1,4,1, 2, 3,2,3, 4,2,4, 3,4,3};
        const int K2_[25] = {2,0,0, 3,1,3,0,1,0, 2,1,1, 4,1,1, 2, 3,3,2, 4,4,2, 4,3,3};
        const float V2_[25] = {P,P,P, -Q,-Q,-Q,-Q,-Q,-Q, -R,-R,-R, Q,Q,Q, -P,
                               -R,-R,-R, P,P,P, -Q,-Q,-Q};
        float s = 0.f;
        #pragma unroll
        for (int q = 0; q < 25; ++q) if (K2_[q] == k)
          s += V2_[q]*x[80+u*5+I2_[q]]*sh[4+J2_[q]];
        t = s * 0.2795084971874737f; }
      tl[wv][idx] = t;
    }
  }
  __syncthreads();

  const short* wrow = (const short*)wch + (size_t)el*3456;
  const float* t = tl[wv];
  float r0 = 0.f, r1 = 0.f, r2 = 0.f;
  #define PATHC(OFF, M1C, NKC, TOFFC, REG)                                  \
    { int v = lane / (NKC), k = lane - v*(NKC);                             \
      const short* wp = wrow + (OFF) + v*(M1C);                             \
      _Pragma("unroll")                                                     \
      for (int ub = 0; ub < (M1C)/8; ++ub) {                                \
        short8 w8 = *(const short8*)(wp + ub*8);                            \
        _Pragma("unroll")                                                   \
        for (int r = 0; r < 8; ++r)                                         \
          REG += us2f((unsigned short)w8[r]) * t[(TOFFC)+(ub*8+r)*(NKC)+k]; \
      } }
  if (lane < 32) {
    PATHC(0,    32, 1, 0,   r0)
    PATHC(2048, 16, 1, 336, r0)
    PATHC(3136,  8, 1, 544, r0)
  }
  if (lane < 48) {
    PATHC(1024, 32, 3, 32,  r1)
    PATHC(1792, 16, 3, 288, r1)
    PATHC(2688, 16, 3, 432, r1)
    PATHC(3008,  8, 3, 520, r1)
  }
  if (lane < 40) {
    PATHC(1536, 32, 5, 128, r2)
    PATHC(2560, 16, 5, 352, r2)
    PATHC(2944,  8, 5, 480, r2)
    PATHC(3392,  8, 5, 552, r2)
  }
  #undef PATHC

  if (live) {
    const float s = 0.3162277660168379f;
    float* ap = agg1 + (size_t)dst*120;
    if (lane < 32) atomicAdd(ap + lane, r0*s);
    if (lane < 48) atomicAdd(ap + 32 + lane, r1*s);
    if (lane < 40) atomicAdd(ap + 80 + lane, r2*s);
  }
}

__global__ void k_out(const float* __restrict__ agg1, const float* __restrict__ node1,
                      const float* __restrict__ sc0e, const float* __restrict__ sc1o,
                      const float* __restrict__ sc2e, float* __restrict__ out) {
  __shared__ float x[120];
  int n = blockIdx.x, tid = threadIdx.x;
  if (tid < 120) x[tid] = node1[(size_t)n*120 + tid];
  __syncthreads();
  if (tid >= 120) return;
  float v = agg1[(size_t)n*120 + tid];
  if (tid < 32) {
    float s = 0.f;
    for (int u = 0; u < 32; ++u) s += x[u]*sc0e[u*32 + tid];
    v += s * 0.1767766952966369f;
  } else if (tid < 80) {
    int jj = tid - 32, vv = jj/3, k = jj - vv*3;
    float s = 0.f;
    for (int u = 0; u < 16; ++u) s += x[32 + u*3 + k]*sc1o[u*16 + vv];
    v += s * 0.25f;
  } else {
    int jj = tid - 80, vv = jj/5, k = jj - vv*5;
    float s = 0.f;
    for (int u = 0; u < 8; ++u) s += x[80 + u*5 + k]*sc2e[u*8 + vv];
    v += s * 0.3535533905932738f;
  }
  out[(size_t)n*120 + tid] = v;
}

// ---------------- launch ----------------
extern "C" void kernel_launch(void* const* d_in, const int* in_sizes, int n_in,
                              void* d_out, int out_size, void* d_ws, size_t ws_size,
                              hipStream_t stream) {
  const float* embed   = (const float*)d_in[1];
  const float* rad_w1  = (const float*)d_in[2];
  const float* rad_b1  = (const float*)d_in[3];
  const float* rad_w2  = (const float*)d_in[4];
  const float* rad_b2  = (const float*)d_in[5];
  const float* wnn0_w1 = (const float*)d_in[6];
  const float* wnn0_w2 = (const float*)d_in[7];
  const float* wnn1_w1 = (const float*)d_in[8];
  const float* wnn1_w2 = (const float*)d_in[9];
  const float* sc0_0e  = (const float*)d_in[10];
  const float* sc1_0e  = (const float*)d_in[11];
  const float* sc1_1o  = (const float*)d_in[12];
  const float* sc1_2e  = (const float*)d_in[13];
  const float* edge_vec = (const float*)d_in[14];
  const float* edge_len = (const float*)d_in[15];
  const int*  anum    = (const int*)d_in[16];
  const int*  ei      = (const int*)d_in[17];

  float* ws = (float*)d_ws;
  float* shbuf = ws;                      // 600000
  float* bc    = ws + 600000;             // 400000
  bf16*  q1b   = (bf16*)(ws + 1000000);   // 1.6M f-slots
  float* node0 = ws + 2600000;            // 320000
  float* W0r   = ws + 2920000;            // 229376
  bf16*  W2t   = (bf16*)(ws + 3149376);   // 110592 f-slots
  float* M0    = ws + 3259968;            // 4096
  float* M1    = ws + 3264064;            // 4096
  float* bias0 = ws + 3268160;            // 64
  float* bias1 = ws + 3268224;            // 64
  float* agg0  = ws + 3268288;            // 600000
  float* agg1  = ws + 3868288;            // 600000
  int*   hist  = (int*)(ws + 4468288);    // 5000   (memset covers)
  int*   cursor= (int*)(ws + 4473288);    // 5000   (memset covers)
  int*   start = (int*)(ws + 4478288);    // 5008
  int*   perm  = (int*)(ws + 4483296);    // 50000
  float* node1 = ws + 4533296;            // 600000
  float* q0    = ws + 5133296;            // 3200000
  bf16*  G0    = (bf16*)(ws + 8333296);   // 8.96M f-slots -> base end 17293296 (69.2 MB)

  long long CH; bf16* wbuf;
  const size_t base_end = 17293296ull;
  if      (ws_size >= (base_end + 43200000ull)*4) { CH = 25000; wbuf = (bf16*)(ws + base_end); }
  else if (ws_size >= (base_end + 21600000ull)*4) { CH = 12500; wbuf = (bf16*)(ws + base_end); }
  else                                            { CH = 6250;  wbuf = (bf16*)(ws + 5133296); } // alias q0+G0

  hipMemsetAsync(agg0, 0, 1210000*sizeof(float), stream);   // agg0+agg1+hist+cursor

  k_setup<<<3222, 256, 0, stream>>>(edge_vec, edge_len, shbuf, bc,
                                    rad_w2, rad_b2, wnn0_w1, wnn1_w1, M0, M1, bias0, bias1,
                                    embed, anum, node0,
                                    wnn0_w2, W0r, wnn1_w2, W2t, ei, hist);
  k_mid<<<1563 + 8750 + 1, 256, 0, stream>>>(bc, rad_w1, rad_b1, M0, M1, bias0, bias1,
                                             q0, q1b, node0, W0r, G0, hist, start);
  k_scat<<<196, 256, 0, stream>>>(ei, start, cursor, perm);
  k_msg0c<<<NN, 256, 0, stream>>>(q0, G0, shbuf, ei, start, perm, agg0);
  k_node1<<<NN, 128, 0, stream>>>(agg0, node0, sc0_0e, node1);

  for (long long e0 = 0; e0 < E_EDGES; e0 += CH) {
    k_wgemm<<<dim3(14, (unsigned)((CH+31)/32), 1), 256, 0, stream>>>(q1b, W2t, wbuf, (int)e0, (int)CH);
    k_tp4<<<(unsigned)((CH+3)/4), 256, 0, stream>>>(wbuf, node1, shbuf, ei, (int)e0, (int)CH, agg1);
  }
  k_out<<<NN, 128, 0, stream>>>(agg1, node1, sc1_0e, sc1_1o, sc1_2e, (float*)d_out);
}

// Round 11
// 543.072 us; speedup vs baseline: 2.2969x; 1.0882x over previous
//
#include <hip/hip_runtime.h>
#include <hip/hip_bf16.h>
#include <math.h>

#define E_EDGES 50000
#define NN 5000

typedef __hip_bfloat16 bf16;
typedef __attribute__((ext_vector_type(8))) short short8;
typedef __attribute__((ext_vector_type(4))) float f32x4;

__device__ __forceinline__ float b2f(bf16 v) { return __bfloat162float(v); }
__device__ __forceinline__ float siluf(float x) { return x / (1.0f + __expf(-x)); }
__device__ __forceinline__ float us2f(unsigned short u) {
  union { unsigned int i; float f; } c; c.i = ((unsigned int)u) << 16; return c.f;
}

// ================= merged setup: prep(+hist) | fuse->Mbb | embed | w0rtb | w2t =================
__global__ void __launch_bounds__(256) k_setup(
    const float* __restrict__ evec, const float* __restrict__ elen,
    float* __restrict__ shb, float* __restrict__ bc,
    const float* __restrict__ w2, const float* __restrict__ b2,
    const float* __restrict__ w01, const float* __restrict__ w11,
    bf16* __restrict__ Mbb,
    float* __restrict__ bias0, float* __restrict__ bias1,
    const float* __restrict__ emb, const int* __restrict__ an,
    float* __restrict__ node0, bf16* __restrict__ node0b,
    const float* __restrict__ w0, bf16* __restrict__ W0rtb,
    const float* __restrict__ w1w2, bf16* __restrict__ W2t,
    const int* __restrict__ ei, int* __restrict__ hist) {
  const int b = blockIdx.x, tid = threadIdx.x;
  if (b < 196) {                      // ---- prep (sh + basis*cutoff) + src histogram
    int e = b*256 + tid;
    if (e >= E_EDGES) return;
    atomicAdd(&hist[ei[e]], 1);
    float x = evec[3*e+0], y = evec[3*e+1], z = evec[3*e+2];
    float r = elen[e];
    float inv = 1.0f / (r + 1e-8f);
    float ux = x*inv, uy = y*inv, uz = z*inv;
    const float s3 = 1.7320508075688772f, s5 = 2.2360679774997896f, s15 = 3.8729833462074170f;
    float* sh = shb + (size_t)e*12;
    sh[0] = 1.0f;
    sh[1] = s3*uy; sh[2] = s3*uz; sh[3] = s3*ux;
    sh[4] = s15*ux*uy; sh[5] = s15*uy*uz; sh[6] = 0.5f*s5*(3.0f*uz*uz - 1.0f);
    sh[7] = s15*ux*uz; sh[8] = 0.5f*s15*(ux*ux - uy*uy);
    sh[9] = 0.f; sh[10] = 0.f; sh[11] = 0.f;
    float rr = fmaxf(r, 1e-8f);
    const float pi = 3.14159265358979f;
    float xr = r * 0.2f;
    float cut = (xr < 1.0f) ? 0.5f*(1.0f + cosf(pi*xr)) : 0.0f;
    float fb = pi * 0.2f;
    for (int k = 1; k <= 8; ++k)
      bc[(size_t)e*8 + (k-1)] = sinf(fb*(float)k*r)/rr * cut;
  } else if (b < 212) {               // ---- fuse rad_w2 into wnn*_w1 -> Mbb (B-layout bf16)
    int i = (b-196)*256 + tid;        // 4096
    int hh = i >> 6, c = i & 63;
    float a0 = 0.f, a1 = 0.f;
    for (int j = 0; j < 64; ++j) {
      float wv = w2[hh*64 + j];
      a0 += wv * w01[j*64 + c];
      a1 += wv * w11[j*64 + c];
    }
    Mbb[(size_t)c*64 + hh]        = __float2bfloat16(a0);   // B[col=c][k=hh] for q0
    Mbb[(size_t)(64 + c)*64 + hh] = __float2bfloat16(a1);   // cols 64..127 for q1
    if (hh == 0) {
      float s0 = 0.f, s1 = 0.f;
      for (int j = 0; j < 64; ++j) {
        s0 += b2[j] * w01[j*64 + c];
        s1 += b2[j] * w11[j*64 + c];
      }
      bias0[c] = s0;
      bias1[c] = s1;
    }
  } else if (b < 1462) {              // ---- embed (320000 exact): fp32 + bf16 copies
    int i = (b-212)*256 + tid;
    int n = i >> 6, c = i & 63;
    float v = emb[an[n]*64 + c];
    node0[i] = v;
    node0b[i] = __float2bfloat16(v);
  } else if (b < 2358) {              // ---- W0rtb[col*64+u] bf16, col = h*56+vp (229376 exact)
    int idx = (b-1462)*256 + tid;
    int col = idx >> 6, u = idx & 63;
    int hh = col / 56, vp = col - hh*56;
    int boff, m3, v;
    if (vp < 32)      { boff = 0;    m3 = 32; v = vp; }
    else if (vp < 48) { boff = 2048; m3 = 16; v = vp - 32; }
    else              { boff = 3072; m3 = 8;  v = vp - 48; }
    W0rtb[idx] = __float2bfloat16(w0[hh*3584 + boff + u*m3 + v]);
  } else {                            // ---- w2t transpose + per-path [v][u] permute
    int idx = (b-2358)*256 + tid;     // 221184 exact
    int nn = idx >> 6, k = idx & 63;
    int p, loc;
    if (nn < 1024)      { p=0;  loc=nn;      }
    else if (nn < 1536) { p=1;  loc=nn-1024; }
    else if (nn < 1792) { p=2;  loc=nn-1536; }
    else if (nn < 2048) { p=3;  loc=nn-1792; }
    else if (nn < 2560) { p=4;  loc=nn-2048; }
    else if (nn < 2688) { p=5;  loc=nn-2560; }
    else if (nn < 2944) { p=6;  loc=nn-2688; }
    else if (nn < 3008) { p=7;  loc=nn-2944; }
    else if (nn < 3136) { p=8;  loc=nn-3008; }
    else if (nn < 3392) { p=9;  loc=nn-3136; }
    else                { p=10; loc=nn-3392; }
    const int M1s[11] = {32,32,32,16,16,16,16,8,8,8,8};
    const int M3s[11] = {32,16,8,16,32,8,16,8,16,32,8};
    int m1 = M1s[p], m3 = M3s[p];
    int v = loc / m1, u = loc - v*m1;
    int src = (nn - loc) + u*m3 + v;
    W2t[idx] = __float2bfloat16(w1w2[(size_t)k*3456 + src]);
  }
}

// ================= k_mid: rad (h-VALU + MFMA q-GEMM) | scan =================
__global__ void __launch_bounds__(256) k_mid(
    const float* __restrict__ bc,
    const float* __restrict__ w1, const float* __restrict__ b1,
    const bf16* __restrict__ Mbb,
    const float* __restrict__ bias0, const float* __restrict__ bias1,
    float* __restrict__ q0, bf16* __restrict__ q1b,
    const int* __restrict__ hist, int* __restrict__ start) {
  __shared__ float smem[1024];
  __shared__ __align__(16) short sHb[2048];
  const int tid = threadIdx.x;
  const int b = blockIdx.x;
  if (b < 1563) {
    float* sW1 = smem;         // 512
    float* sB  = smem + 512;   // 64
    float* sb0 = smem + 576;   // 64
    float* sb1 = smem + 640;   // 64
    float* sBC = smem + 704;   // 256
    const int j = tid >> 6, m = tid & 63;
    for (int i = tid; i < 512; i += 256) sW1[i] = w1[i];
    if (tid < 64) { sB[tid] = b1[tid]; sb0[tid] = bias0[tid]; sb1[tid] = bias1[tid]; }
    {
      int e = b*32 + (tid >> 3);
      int k = tid & 7;
      int eL = e < E_EDGES ? e : E_EDGES-1;
      sBC[tid] = bc[(size_t)eL*8 + k];
    }
    __syncthreads();
    // phase 1: h = silu(basis @ W1 + b1) -> bf16 LDS
    #pragma unroll
    for (int g = 0; g < 8; ++g) {
      int el = g*4 + j;
      float t = sB[m];
      #pragma unroll
      for (int k = 0; k < 8; ++k) t += sBC[el*8+k]*sW1[k*64+m];
      bf16 hv = __float2bfloat16(siluf(t));
      sHb[el*64 + m] = *(short*)&hv;
    }
    __syncthreads();
    // phase 2: q = silu(h @ M + bias) via MFMA; wave -> (mtile, colgroup)
    const int w = tid >> 6, lane = tid & 63;
    const int row16 = lane & 15, quad = lane >> 4;
    const int mtile = w & 1, cg = w >> 1;
    const short* ap = sHb + (mtile*16 + row16)*64 + quad*8;
    short8 a0 = *(const short8*)ap;
    short8 a1 = *(const short8*)(ap + 32);
    f32x4 acc[4] = {};
    #pragma unroll
    for (int ni = 0; ni < 4; ++ni) {
      const short* bp = (const short*)Mbb + (size_t)(cg*64 + ni*16 + row16)*64 + quad*8;
      short8 b0 = *(const short8*)bp;
      short8 b1v = *(const short8*)(bp + 32);
      acc[ni] = __builtin_amdgcn_mfma_f32_16x16x32_bf16(a0, b0, acc[ni], 0,0,0);
      acc[ni] = __builtin_amdgcn_mfma_f32_16x16x32_bf16(a1, b1v, acc[ni], 0,0,0);
    }
    const float* bias = cg ? sb1 : sb0;
    #pragma unroll
    for (int ni = 0; ni < 4; ++ni) {
      int c = ni*16 + row16;
      float bv = bias[c];
      #pragma unroll
      for (int r = 0; r < 4; ++r) {
        int e = b*32 + mtile*16 + quad*4 + r;
        if (e < E_EDGES) {
          float val = siluf(acc[ni][r] + bv);
          if (cg == 0) q0[(size_t)e*64 + c] = val;
          else         q1b[(size_t)e*64 + c] = __float2bfloat16(val);
        }
      }
    }
  } else {
    // ---- exclusive scan: hist[0..5000) -> start[0..5000]
    int* sp = (int*)smem;
    int base = tid*20;
    int localsum = 0;
    for (int i = 0; i < 20; ++i) { int jj = base+i; localsum += (jj < NN) ? hist[jj] : 0; }
    sp[tid] = localsum;
    __syncthreads();
    if (tid == 0) {
      int acc = 0;
      for (int i = 0; i < 256; ++i) { int t = sp[i]; sp[i] = acc; acc += t; }
    }
    __syncthreads();
    int run = sp[tid];
    for (int i = 0; i < 20; ++i) {
      int jj = base+i;
      if (jj < NN) { start[jj] = run; run += hist[jj]; }
    }
    if (tid == 255) start[NN] = run;
  }
}

// ================= generic MFMA GEMM: out[r, :] = A[r, :64] @ B([col][64k]) =================
__global__ void __launch_bounds__(256) k_bgemm(
    const bf16* __restrict__ A, const bf16* __restrict__ B,
    bf16* __restrict__ out, int stride, int ntiles, int e0, int nE) {
  __shared__ short lds[4][32*64];
  const int tid = threadIdx.x;
  const int wid = tid >> 6, lane = tid & 63;
  const int nt = blockIdx.x*4 + wid;
  const int r0 = blockIdx.y*32;
  const int row16 = lane & 15, quad = lane >> 4;

  short8 a[2][2];
  #pragma unroll
  for (int mi = 0; mi < 2; ++mi) {
    int r = r0 + mi*16 + row16;
    int rg = e0 + ((r < nE) ? r : 0);
    const short* ap = (const short*)A + (size_t)rg*64 + quad*8;
    a[mi][0] = *(const short8*)(ap);
    a[mi][1] = *(const short8*)(ap + 32);
  }
  if (nt < ntiles) {
    f32x4 acc[4][2] = {};
    #pragma unroll
    for (int ni = 0; ni < 4; ++ni) {
      int col = nt*64 + ni*16 + row16;
      const short* bp = (const short*)B + (size_t)col*64 + quad*8;
      short8 b0 = *(const short8*)(bp);
      short8 b1 = *(const short8*)(bp + 32);
      #pragma unroll
      for (int mi = 0; mi < 2; ++mi) {
        acc[ni][mi] = __builtin_amdgcn_mfma_f32_16x16x32_bf16(a[mi][0], b0, acc[ni][mi], 0,0,0);
        acc[ni][mi] = __builtin_amdgcn_mfma_f32_16x16x32_bf16(a[mi][1], b1, acc[ni][mi], 0,0,0);
      }
    }
    #pragma unroll
    for (int ni = 0; ni < 4; ++ni)
      #pragma unroll
      for (int mi = 0; mi < 2; ++mi)
        #pragma unroll
        for (int rr = 0; rr < 4; ++rr) {
          bf16 hv = __float2bfloat16(acc[ni][mi][rr]);
          lds[wid][(mi*16 + quad*4 + rr)*64 + ni*16 + row16] = *(short*)&hv;
        }
  }
  __syncthreads();
  if (nt < ntiles) {
    #pragma unroll
    for (int it = 0; it < 4; ++it) {
      int unit = it*64 + lane;
      int rrow = unit >> 3;
      int cu = (unit & 7) * 8;
      int r = r0 + rrow;
      if (r < nE)
        *(uint4*)((short*)out + (size_t)r*stride + nt*64 + cu) =
            *(const uint4*)&lds[wid][rrow*64 + cu];
    }
  }
}

// ================= CSR scatter: perm = edges sorted by src =================
__global__ void k_scat(const int* __restrict__ ei, const int* __restrict__ start,
                       int* __restrict__ cursor, int* __restrict__ perm) {
  int e = blockIdx.x*256 + threadIdx.x;
  if (e >= E_EDGES) return;
  int src = ei[e];
  int pos = start[src] + atomicAdd(&cursor[src], 1);
  perm[pos] = e;
}

// ================= layer-0 message: per-node; G0 row staged in LDS once =================
__global__ void __launch_bounds__(256) k_msg0c(
    const float* __restrict__ q0, const bf16* __restrict__ G0,
    const float* __restrict__ shb, const int* __restrict__ ei,
    const int* __restrict__ start, const int* __restrict__ perm,
    float* __restrict__ agg0) {
  __shared__ uint4 g4[448];          // G0 row n: [h*56+vp], 3584 bf16
  __shared__ float sq[4][64];
  const int n = blockIdx.x;
  const int tid = threadIdx.x;
  const int wv = tid >> 6, lane = tid & 63;
  const uint4* gr = (const uint4*)(G0 + (size_t)n*3584);
  for (int i = tid; i < 448; i += 256) g4[i] = gr[i];
  const int s0 = start[n], s1 = start[n+1];
  __syncthreads();
  const short* gs = (const short*)g4;
  const float c = 0.125f * 0.3162277660168379f;
  for (int base = s0; base < s1; base += 4) {
    int idx = base + wv;
    if (idx < s1) {
      int e = perm[idx];
      sq[wv][lane] = q0[(size_t)e*64 + lane];
      float z = 0.f;
      if (lane < 56) {
        #pragma unroll
        for (int h = 0; h < 64; ++h)
          z += sq[wv][h]*us2f((unsigned short)gs[h*56 + lane]);
      }
      int dst = ei[E_EDGES + e];
      float* ap = agg0 + (size_t)dst*120;
      const float* sh = shb + (size_t)e*12;
      if (lane < 32) {
        atomicAdd(ap + lane, z*c);
      } else if (lane < 48) {
        int v = lane - 32;
        #pragma unroll
        for (int k = 0; k < 3; ++k) atomicAdd(ap + 32 + v*3 + k, z*sh[1+k]*c);
      } else if (lane < 56) {
        int v = lane - 48;
        #pragma unroll
        for (int k = 0; k < 5; ++k) atomicAdd(ap + 80 + v*5 + k, z*sh[4+k]*c);
      }
    }
  }
}

__global__ void k_node1(const float* __restrict__ agg0, const float* __restrict__ node0,
                        const float* __restrict__ sc00, float* __restrict__ node1) {
  __shared__ float n0[64];
  int n = blockIdx.x, tid = threadIdx.x;
  if (tid < 64) n0[tid] = node0[(size_t)n*64 + tid];
  __syncthreads();
  if (tid >= 120) return;
  float v = agg0[(size_t)n*120 + tid];
  if (tid < 32) {
    float s = 0.f;
    for (int u = 0; u < 64; ++u) s += n0[u]*sc00[u*32 + tid];
    v += s * 0.125f;
    v = siluf(v);
  }
  node1[(size_t)n*120 + tid] = v;
}

// ================= layer-1 consume: one wave/edge; w via global short8; reg accum =================
__global__ void __launch_bounds__(256) k_tp4(
    const bf16* __restrict__ wch, const float* __restrict__ node1,
    const float* __restrict__ shb, const int* __restrict__ ei,
    int e0, int nE, float* __restrict__ agg1) {
  __shared__ float tl[4][592];
  __shared__ float xl[4][120];
  __shared__ float shl[4][12];
  const int tid = threadIdx.x;
  const int wv = tid >> 6, lane = tid & 63;
  int elr = blockIdx.x*4 + wv;
  const bool live = elr < nE;
  const int el = live ? elr : nE-1;
  const int eg = e0 + el;
  const int src = ei[eg], dst = ei[E_EDGES + eg];

  for (int i = lane; i < 120; i += 64) xl[wv][i] = node1[(size_t)src*120 + i];
  if (lane < 12) shl[wv][lane] = shb[(size_t)eg*12 + lane];
  __syncthreads();

  {
    const float* x  = xl[wv];
    const float* sh = shl[wv];
    const float A = 0.3162277660168379f, Bc = 0.1825741858350554f, B2 = 0.3651483716701107f;
    const int I_[11] = {0,2,0,1,1,2, 0,1,2, 0,2};
    const int J_[11] = {2,0,1,0,2,1, 0,1,2, 0,2};
    const int K_[11] = {0,0,1,1,3,3, 2,2,2, 4,4};
    const float V_[11] = {A,A,A,A,A,A, -Bc,B2,-Bc, -A,A};
    for (int idx = lane; idx < 592; idx += 64) {
      float t = 0.0f;
      if (idx < 32)       { t = x[idx] * 0.1336306209562122f; }
      else if (idx < 128) { int j = idx-32,  u=j/3, k=j-u*3; t = x[u]*sh[1+k] * 0.1178511301977579f; }
      else if (idx < 288) { int j = idx-128, u=j/5, k=j-u*5; t = x[u]*sh[4+k] * 0.125f; }
      else if (idx < 336) { int j = idx-288, u=j/3, k=j-u*3; t = x[32+u*3+k] * 0.1178511301977579f; }
      else if (idx < 352) { int u = idx-336;
        t = (x[32+u*3]*sh[1] + x[32+u*3+1]*sh[2] + x[32+u*3+2]*sh[3]) * 0.0771516749810460f; }
      else if (idx < 432) { int j = idx-352, u=j/5, k=j-u*5;
        float s = 0.f;
        #pragma unroll
        for (int q = 0; q < 11; ++q) if (K_[q] == k)
          s += V_[q]*x[32+u*3+I_[q]]*sh[1+J_[q]];
        t = s * 0.2795084971874737f; }
      else if (idx < 480) { int j = idx-432, u=j/3, k=j-u*3;
        float s = 0.f;
        #pragma unroll
        for (int q = 0; q < 11; ++q) if (J_[q] == k)
          s += V_[q]*x[32+u*3+I_[q]]*sh[4+K_[q]];
        t = s * 0.2041241452319315f; }
      else if (idx < 520) { int j = idx-480, u=j/5, k=j-u*5; t = x[80+u*5+k] * 0.125f; }
      else if (idx < 544) { int j = idx-520, u=j/3, k=j-u*3;
        float s = 0.f;
        #pragma unroll
        for (int q = 0; q < 11; ++q) if (J_[q] == k)
          s += V_[q]*x[80+u*5+K_[q]]*sh[1+I_[q]];
        t = s * 0.2041241452319315f; }
      else if (idx < 552) { int u = idx-544;
        float s = 0.f;
        #pragma unroll
        for (int q = 0; q < 5; ++q) s += x[80+u*5+q]*sh[4+q];
        t = s * 0.0597614304667197f; }
      else { int j = idx-552, u=j/5, k=j-u*5;
        const float P = 0.2390457218668787f, Q = 0.2070196678027063f, R = 0.1195228609334394f;
        const int I2_[25] = {0,0,2, 0,0,1,1,3,3, 1,1,2, 1,1,4, 2, 2,3,3, 2,4,4, 3,3,4};
        const int J2_[25] = {0,2,0, 1,3,0,3,0,1, 1,2,1, 1,4,1, 2, 3,2,3, 4,2,4, 3,4,3};
        const int K2_[25] = {2,0,0, 3,1,3,0,1,0, 2,1,1, 4,1,1, 2, 3,3,2, 4,4,2, 4,3,3};
        const float V2_[25] = {P,P,P, -Q,-Q,-Q,-Q,-Q,-Q, -R,-R,-R, Q,Q,Q, -P,
                               -R,-R,-R, P,P,P, -Q,-Q,-Q};
        float s = 0.f;
        #pragma unroll
        for (int q = 0; q < 25; ++q) if (K2_[q] == k)
          s += V2_[q]*x[80+u*5+I2_[q]]*sh[4+J2_[q]];
        t = s * 0.2795084971874737f; }
      tl[wv][idx] = t;
    }
  }
  __syncthreads();

  const short* wrow = (const short*)wch + (size_t)el*3456;
  const float* t = tl[wv];
  float r0 = 0.f, r1 = 0.f, r2 = 0.f;
  #define PATHC(OFF, M1C, NKC, TOFFC, REG)                                  \
    { int v = lane / (NKC), k = lane - v*(NKC);                             \
      const short* wp = wrow + (OFF) + v*(M1C);                             \
      _Pragma("unroll")                                                     \
      for (int ub = 0; ub < (M1C)/8; ++ub) {                                \
        short8 w8 = *(const short8*)(wp + ub*8);                            \
        _Pragma("unroll")                                                   \
        for (int r = 0; r < 8; ++r)                                         \
          REG += us2f((unsigned short)w8[r]) * t[(TOFFC)+(ub*8+r)*(NKC)+k]; \
      } }
  if (lane < 32) {
    PATHC(0,    32, 1, 0,   r0)
    PATHC(2048, 16, 1, 336, r0)
    PATHC(3136,  8, 1, 544, r0)
  }
  if (lane < 48) {
    PATHC(1024, 32, 3, 32,  r1)
    PATHC(1792, 16, 3, 288, r1)
    PATHC(2688, 16, 3, 432, r1)
    PATHC(3008,  8, 3, 520, r1)
  }
  if (lane < 40) {
    PATHC(1536, 32, 5, 128, r2)
    PATHC(2560, 16, 5, 352, r2)
    PATHC(2944,  8, 5, 480, r2)
    PATHC(3392,  8, 5, 552, r2)
  }
  #undef PATHC

  if (live) {
    const float s = 0.3162277660168379f;
    float* ap = agg1 + (size_t)dst*120;
    if (lane < 32) atomicAdd(ap + lane, r0*s);
    if (lane < 48) atomicAdd(ap + 32 + lane, r1*s);
    if (lane < 40) atomicAdd(ap + 80 + lane, r2*s);
  }
}

__global__ void k_out(const float* __restrict__ agg1, const float* __restrict__ node1,
                      const float* __restrict__ sc0e, const float* __restrict__ sc1o,
                      const float* __restrict__ sc2e, float* __restrict__ out) {
  __shared__ float x[120];
  int n = blockIdx.x, tid = threadIdx.x;
  if (tid < 120) x[tid] = node1[(size_t)n*120 + tid];
  __syncthreads();
  if (tid >= 120) return;
  float v = agg1[(size_t)n*120 + tid];
  if (tid < 32) {
    float s = 0.f;
    for (int u = 0; u < 32; ++u) s += x[u]*sc0e[u*32 + tid];
    v += s * 0.1767766952966369f;
  } else if (tid < 80) {
    int jj = tid - 32, vv = jj/3, k = jj - vv*3;
    float s = 0.f;
    for (int u = 0; u < 16; ++u) s += x[32 + u*3 + k]*sc1o[u*16 + vv];
    v += s * 0.25f;
  } else {
    int jj = tid - 80, vv = jj/5, k = jj - vv*5;
    float s = 0.f;
    for (int u = 0; u < 8; ++u) s += x[80 + u*5 + k]*sc2e[u*8 + vv];
    v += s * 0.3535533905932738f;
  }
  out[(size_t)n*120 + tid] = v;
}

// ---------------- launch ----------------
extern "C" void kernel_launch(void* const* d_in, const int* in_sizes, int n_in,
                              void* d_out, int out_size, void* d_ws, size_t ws_size,
                              hipStream_t stream) {
  const float* embed   = (const float*)d_in[1];
  const float* rad_w1  = (const float*)d_in[2];
  const float* rad_b1  = (const float*)d_in[3];
  const float* rad_w2  = (const float*)d_in[4];
  const float* rad_b2  = (const float*)d_in[5];
  const float* wnn0_w1 = (const float*)d_in[6];
  const float* wnn0_w2 = (const float*)d_in[7];
  const float* wnn1_w1 = (const float*)d_in[8];
  const float* wnn1_w2 = (const float*)d_in[9];
  const float* sc0_0e  = (const float*)d_in[10];
  const float* sc1_0e  = (const float*)d_in[11];
  const float* sc1_1o  = (const float*)d_in[12];
  const float* sc1_2e  = (const float*)d_in[13];
  const float* edge_vec = (const float*)d_in[14];
  const float* edge_len = (const float*)d_in[15];
  const int*  anum    = (const int*)d_in[16];
  const int*  ei      = (const int*)d_in[17];

  float* ws = (float*)d_ws;
  float* shbuf = ws;                        // 600000
  float* bc    = ws + 600000;               // 400000
  bf16*  q1b   = (bf16*)(ws + 1000000);     // 1.6M f-slots
  float* node0 = ws + 2600000;              // 320000
  bf16*  node0b= (bf16*)(ws + 2920000);     // 160000 f-slots
  bf16*  W0rtb = (bf16*)(ws + 3080000);     // 114688 f-slots
  bf16*  W2t   = (bf16*)(ws + 3194688);     // 110592 f-slots
  bf16*  Mbb   = (bf16*)(ws + 3305280);     // 4096 f-slots
  float* bias0 = ws + 3309376;              // 64
  float* bias1 = ws + 3309440;              // 64
  float* agg0  = ws + 3309504;              // 600000
  float* agg1  = ws + 3909504;              // 600000
  int*   hist  = (int*)(ws + 4509504);      // 5000   (memset covers)
  int*   cursor= (int*)(ws + 4514504);      // 5000   (memset covers)
  int*   start = (int*)(ws + 4519504);      // 5008
  int*   perm  = (int*)(ws + 4524512);      // 50000
  float* node1 = ws + 4574512;              // 600000
  float* q0    = ws + 5174512;              // 3200000
  bf16*  G0    = (bf16*)(ws + 8374512);     // 8.96M f-slots -> base end 17334512 (69.3 MB)

  long long CH; bf16* wbuf;
  const size_t base_end = 17334512ull;
  if      (ws_size >= (base_end + 43200000ull)*4) { CH = 25000; wbuf = (bf16*)(ws + base_end); }
  else if (ws_size >= (base_end + 21600000ull)*4) { CH = 12500; wbuf = (bf16*)(ws + base_end); }
  else                                            { CH = 6250;  wbuf = (bf16*)(ws + 5174512); } // alias q0+G0

  hipMemsetAsync(agg0, 0, 1210000*sizeof(float), stream);   // agg0+agg1+hist+cursor

  k_setup<<<3222, 256, 0, stream>>>(edge_vec, edge_len, shbuf, bc,
                                    rad_w2, rad_b2, wnn0_w1, wnn1_w1, Mbb, bias0, bias1,
                                    embed, anum, node0, node0b,
                                    wnn0_w2, W0rtb, wnn1_w2, W2t, ei, hist);
  k_mid<<<1564, 256, 0, stream>>>(bc, rad_w1, rad_b1, Mbb, bias0, bias1,
                                  q0, q1b, hist, start);
  k_bgemm<<<dim3(14, (NN+31)/32), 256, 0, stream>>>(node0b, W0rtb, G0, 3584, 56, 0, NN);
  k_scat<<<196, 256, 0, stream>>>(ei, start, cursor, perm);
  k_msg0c<<<NN, 256, 0, stream>>>(q0, G0, shbuf, ei, start, perm, agg0);
  k_node1<<<NN, 128, 0, stream>>>(agg0, node0, sc0_0e, node1);

  for (long long e0 = 0; e0 < E_EDGES; e0 += CH) {
    k_bgemm<<<dim3(14, (unsigned)((CH+31)/32), 1), 256, 0, stream>>>(q1b, W2t, wbuf, 3456, 54, (int)e0, (int)CH);
    k_tp4<<<(unsigned)((CH+3)/4), 256, 0, stream>>>(wbuf, node1, shbuf, ei, (int)e0, (int)CH, agg1);
  }
  k_out<<<NN, 128, 0, stream>>>(agg1, node1, sc1_0e, sc1_1o, sc1_2e, (float*)d_out);
}